// Round 1
// baseline (365.513 us; speedup 1.0000x reference)
//
#include <hip/hip_runtime.h>
#include <math.h>

#define HD 128
#define WD 128
#define CIN 64
#define COUT 64
#define NB 4
#define K2 9
#define HW (HD*WD)          // 16384
#define CK 576              // CIN*K2
#define TP 16               // pixels per block in deform kernel

// ---------------- Kernel 0: transpose weight [o][ck] -> wt[ck][o] ----------------
__global__ void transpose_w_kernel(const float* __restrict__ w, float* __restrict__ wt) {
    int i = blockIdx.x * 256 + threadIdx.x;   // i = o*576 + ck, total 36864
    int o = i / CK;
    int ck = i - o * CK;
    wt[ck * COUT + o] = w[i];
}

// ---------------- Kernel 1: fused offset+mask conv, sigmoid, modulation ----------------
// out: offy[n][k][ho][wo], offx[n][k][ho][wo]  (already multiplied by mask)
__global__ __launch_bounds__(128) void offmask_kernel(
    const float* __restrict__ x,
    const float* __restrict__ w_off, const float* __restrict__ b_off,
    const float* __restrict__ w_mask, const float* __restrict__ b_mask,
    float* __restrict__ offy, float* __restrict__ offx)
{
    // LDS: combined weights rearranged [ci*9+tap][j], j=0..17 -> w_off ch j, j=18..26 -> w_mask ch j-18
    __shared__ float ws[CK][28];   // pad 27 -> 28
    int t = threadIdx.x;
    for (int i = t; i < CK * 27; i += 128) {
        int j = i % 27;
        int citap = i / 27;
        int ci = citap / 9;
        int tap = citap - ci * 9;
        float v;
        if (j < 18) v = w_off[(j * CIN + ci) * 9 + tap];
        else        v = w_mask[((j - 18) * CIN + ci) * 9 + tap];
        ws[citap][j] = v;
    }
    __syncthreads();

    int pix = blockIdx.x * 128 + t;      // 0..65535
    int n  = pix >> 14;
    int ho = (pix >> 7) & 127;
    int wo = pix & 127;

    float acc[27];
    #pragma unroll
    for (int j = 0; j < 18; j++) acc[j] = b_off[j];
    #pragma unroll
    for (int j = 0; j < 9; j++)  acc[18 + j] = b_mask[j];

    // precompute tap offsets & validity (same for all ci)
    int offs[9];
    bool oks[9];
    #pragma unroll
    for (int dy = 0; dy < 3; dy++) {
        int y = ho - 1 + dy;
        #pragma unroll
        for (int dx = 0; dx < 3; dx++) {
            int xx = wo - 1 + dx;
            bool ok = (y >= 0) && (y < HD) && (xx >= 0) && (xx < WD);
            oks[dy * 3 + dx] = ok;
            offs[dy * 3 + dx] = (ok ? y : 0) * WD + (ok ? xx : 0);
        }
    }

    const float* xn = x + n * CIN * HW;
    for (int ci = 0; ci < CIN; ci++) {
        const float* xc = xn + ci * HW;
        float v[9];
        #pragma unroll
        for (int tap = 0; tap < 9; tap++)
            v[tap] = oks[tap] ? xc[offs[tap]] : 0.f;
        #pragma unroll
        for (int tap = 0; tap < 9; tap++) {
            const float* wrow = ws[ci * 9 + tap];
            float vv = v[tap];
            #pragma unroll
            for (int j = 0; j < 27; j++) acc[j] += wrow[j] * vv;
        }
    }

    // sigmoid masks
    float m[9];
    #pragma unroll
    for (int j = 0; j < 9; j++) m[j] = 1.f / (1.f + expf(-acc[18 + j]));

    // offset ch c multiplied by mask ch (c<9 ? c : c-9); off_y = ch 2k, off_x = ch 2k+1
    #pragma unroll
    for (int k = 0; k < 9; k++) {
        int cy = 2 * k;
        int cx = 2 * k + 1;
        float my = m[cy < 9 ? cy : cy - 9];
        float mx = m[cx < 9 ? cx : cx - 9];
        int o = ((n * K2 + k) * HD + ho) * WD + wo;
        offy[o] = acc[cy] * my;
        offx[o] = acc[cx] * mx;
    }
}

// ---------------- Kernel 2: deformable sampling + contraction ----------------
// grid: (WD/TP, HD, NB), block 256
__global__ __launch_bounds__(256) void deform_kernel(
    const float* __restrict__ x,
    const float* __restrict__ offy, const float* __restrict__ offx,
    const float* __restrict__ wt,     // [ck][o]  576 x 64
    const float* __restrict__ bias,
    float* __restrict__ out)
{
    __shared__ __align__(16) float val_s[CK * TP];   // [row=c*9+k][p], 36864 B
    __shared__ float4 p_w4[K2 * TP];                 // bilinear weights (validity folded)
    __shared__ int4   p_idx4[K2 * TP];               // clamped gather indices

    int t = threadIdx.x;
    int wo0 = blockIdx.x * TP;
    int ho  = blockIdx.y;
    int n   = blockIdx.z;

    // ---- Phase A0: bilinear params for (k, p) ----
    if (t < K2 * TP) {
        int k = t >> 4;
        int p = t & 15;
        int wo = wo0 + p;
        int oi = ((n * K2 + k) * HD + ho) * WD + wo;
        float oy = offy[oi];
        float ox = offx[oi];
        int ki = k / 3, kj = k - ki * 3;
        float py = (float)(ho - 1 + ki) + oy;
        float px = (float)(wo - 1 + kj) + ox;
        float y0f = floorf(py), x0f = floorf(px);
        float wy = py - y0f, wx = px - x0f;
        int y0 = (int)y0f, x0 = (int)x0f;
        float wy0 = 1.f - wy, wx0 = 1.f - wx;

        int y0c = min(max(y0, 0), HD - 1);
        int y1c = min(max(y0 + 1, 0), HD - 1);
        int x0c = min(max(x0, 0), WD - 1);
        int x1c = min(max(x0 + 1, 0), WD - 1);
        bool vy0 = (y0 >= 0) && (y0 < HD);
        bool vy1 = (y0 + 1 >= 0) && (y0 + 1 < HD);
        bool vx0 = (x0 >= 0) && (x0 < WD);
        bool vx1 = (x0 + 1 >= 0) && (x0 + 1 < WD);

        float4 w4;
        w4.x = (vy0 && vx0) ? wy0 * wx0 : 0.f;
        w4.y = (vy0 && vx1) ? wy0 * wx  : 0.f;
        w4.z = (vy1 && vx0) ? wy  * wx0 : 0.f;
        w4.w = (vy1 && vx1) ? wy  * wx  : 0.f;
        int4 i4;
        i4.x = y0c * WD + x0c;
        i4.y = y0c * WD + x1c;
        i4.z = y1c * WD + x0c;
        i4.w = y1c * WD + x1c;
        p_w4[t] = w4;
        p_idx4[t] = i4;
    }
    __syncthreads();

    // ---- Phase A: gather val[row][p] ----
    const float* xn = x + n * CIN * HW;
    for (int e = t; e < CK * TP; e += 256) {
        int row = e >> 4;          // c*9+k
        int p = e & 15;
        int c = row / 9;
        int k = row - c * 9;
        int task = (k << 4) | p;
        float4 w4 = p_w4[task];
        int4  i4 = p_idx4[task];
        const float* xc = xn + c * HW;
        float g = w4.x * xc[i4.x] + w4.y * xc[i4.y]
                + w4.z * xc[i4.z] + w4.w * xc[i4.w];
        val_s[e] = g;
    }
    __syncthreads();

    // ---- Phase B: out[o][p] = sum_r wt[r][o] * val[r][p] ----
    int o = t & 63;
    int q = t >> 6;       // pixel quad: p = q*4 + j
    float4 acc = {0.f, 0.f, 0.f, 0.f};
    const float4* v4 = (const float4*)val_s;
    const float* wp = wt + o;
    #pragma unroll 4
    for (int r = 0; r < CK; r++) {
        float w = wp[r * COUT];
        float4 vv = v4[r * 4 + q];
        acc.x += w * vv.x;
        acc.y += w * vv.y;
        acc.z += w * vv.z;
        acc.w += w * vv.w;
    }
    float b = bias[o];
    acc.x += b; acc.y += b; acc.z += b; acc.w += b;

    __syncthreads();                    // done reading val_s
    float4* o4 = (float4*)val_s;        // reuse as out staging [o][p]
    o4[o * 4 + q] = acc;
    __syncthreads();

    // coalesced-ish write: 1024 floats, 16-consecutive per (o) row
    int obase = (n * COUT) * HW + ho * WD + wo0;
    #pragma unroll
    for (int i = 0; i < 4; i++) {
        int l = t + 256 * i;
        int oo = l >> 4;
        int p = l & 15;
        out[obase + oo * HW + p] = val_s[l];
    }
}

extern "C" void kernel_launch(void* const* d_in, const int* in_sizes, int n_in,
                              void* d_out, int out_size, void* d_ws, size_t ws_size,
                              hipStream_t stream) {
    const float* x      = (const float*)d_in[0];
    const float* w_off  = (const float*)d_in[1];
    const float* b_off  = (const float*)d_in[2];
    const float* w_mask = (const float*)d_in[3];
    const float* b_mask = (const float*)d_in[4];
    const float* weight = (const float*)d_in[5];
    const float* bias   = (const float*)d_in[6];
    float* out = (float*)d_out;

    // workspace layout (floats): offy | offx | wt
    float* offy = (float*)d_ws;
    float* offx = offy + (size_t)NB * K2 * HW;    // 589824
    float* wt   = offx + (size_t)NB * K2 * HW;    // +589824, wt = 36864 floats

    transpose_w_kernel<<<144, 256, 0, stream>>>(weight, wt);
    offmask_kernel<<<512, 128, 0, stream>>>(x, w_off, b_off, w_mask, b_mask, offy, offx);
    deform_kernel<<<dim3(WD / TP, HD, NB), 256, 0, stream>>>(x, offy, offx, wt, bias, out);
}

// Round 2
// 345.323 us; speedup vs baseline: 1.0585x; 1.0585x over previous
//
#include <hip/hip_runtime.h>
#include <math.h>

#define HD 128
#define WD 128
#define CIN 64
#define COUT 64
#define NB 4
#define K2 9
#define HW (HD*WD)          // 16384
#define CK 576              // CIN*K2
#define TP 16               // pixels per block in deform kernel
#define VROW 20             // padded val_s row stride (floats), mult of 4 for float4 align

#define OFFSZ ((size_t)NB * K2 * HW)     // 589824 floats per offset plane
#define WTSZ  ((size_t)CK * COUT)        // 36864 floats
#define XTSZ  ((size_t)NB * HW * CIN)    // 4194304 floats

// ---------------- Kernel 0: transpose weight [o][ck] -> wt[ck][o] ----------------
__global__ void transpose_w_kernel(const float* __restrict__ w, float* __restrict__ wt) {
    int i = blockIdx.x * 256 + threadIdx.x;   // i = o*576 + ck, total 36864
    int o = i / CK;
    int ck = i - o * CK;
    wt[ck * COUT + o] = w[i];
}

// ---------------- Kernel 0b: transpose x NCHW -> NHWC ----------------
// grid (W/64, H, N), block 256
__global__ __launch_bounds__(256) void transpose_x_kernel(const float* __restrict__ x,
                                                          float* __restrict__ xT) {
    __shared__ float tile[64][65];
    int t = threadIdx.x;
    int w0 = blockIdx.x * 64;
    int h  = blockIdx.y;
    int n  = blockIdx.z;
    int g  = t >> 6;          // 0..3
    int wl = t & 63;
    const float* xb = x + ((size_t)n * CIN) * HW + h * WD + w0;
    #pragma unroll
    for (int i = 0; i < 16; i++) {
        int cc = i * 4 + g;
        tile[cc][wl] = xb[(size_t)cc * HW + wl];
    }
    __syncthreads();
    float* xo = xT + ((size_t)n * HW + (size_t)h * WD + w0) * CIN;
    int cl = t & 63;
    #pragma unroll
    for (int i = 0; i < 16; i++) {
        int ww = i * 4 + g;
        xo[(size_t)ww * CIN + cl] = tile[cl][ww];
    }
}

// ---------------- Kernel 1: fused offset+mask conv, sigmoid, modulation ----------------
__global__ __launch_bounds__(256) void offmask_kernel(
    const float* __restrict__ x,
    const float* __restrict__ w_off, const float* __restrict__ b_off,
    const float* __restrict__ w_mask, const float* __restrict__ b_mask,
    float* __restrict__ offy, float* __restrict__ offx)
{
    __shared__ float ws[CK][27];   // [ci*9+tap][j]; j<18 off ch, j>=18 mask ch
    int t = threadIdx.x;
    for (int i = t; i < CK * 27; i += 256) {
        int j = i % 27;
        int citap = i / 27;
        int ci = citap / 9;
        int tap = citap - ci * 9;
        float v;
        if (j < 18) v = w_off[(j * CIN + ci) * 9 + tap];
        else        v = w_mask[((j - 18) * CIN + ci) * 9 + tap];
        ws[citap][j] = v;
    }
    __syncthreads();

    int pix = blockIdx.x * 256 + t;      // 0..65535
    int n  = pix >> 14;
    int ho = (pix >> 7) & 127;
    int wo = pix & 127;

    float acc[27];
    #pragma unroll
    for (int j = 0; j < 18; j++) acc[j] = b_off[j];
    #pragma unroll
    for (int j = 0; j < 9; j++)  acc[18 + j] = b_mask[j];

    int offs[9];
    bool oks[9];
    #pragma unroll
    for (int dy = 0; dy < 3; dy++) {
        int y = ho - 1 + dy;
        #pragma unroll
        for (int dx = 0; dx < 3; dx++) {
            int xx = wo - 1 + dx;
            bool ok = (y >= 0) && (y < HD) && (xx >= 0) && (xx < WD);
            oks[dy * 3 + dx] = ok;
            offs[dy * 3 + dx] = (ok ? y : 0) * WD + (ok ? xx : 0);
        }
    }

    const float* xn = x + (size_t)n * CIN * HW;
    for (int ci = 0; ci < CIN; ci++) {
        const float* xc = xn + (size_t)ci * HW;
        float v[9];
        #pragma unroll
        for (int tap = 0; tap < 9; tap++)
            v[tap] = oks[tap] ? xc[offs[tap]] : 0.f;
        #pragma unroll
        for (int tap = 0; tap < 9; tap++) {
            const float* wrow = ws[ci * 9 + tap];
            float vv = v[tap];
            #pragma unroll
            for (int j = 0; j < 27; j++) acc[j] += wrow[j] * vv;
        }
    }

    float m[9];
    #pragma unroll
    for (int j = 0; j < 9; j++) m[j] = 1.f / (1.f + expf(-acc[18 + j]));

    #pragma unroll
    for (int k = 0; k < 9; k++) {
        int cy = 2 * k;
        int cx = 2 * k + 1;
        float my = m[cy < 9 ? cy : cy - 9];
        float mx = m[cx < 9 ? cx : cx - 9];
        size_t o = (((size_t)n * K2 + k) * HD + ho) * WD + wo;
        offy[o] = acc[cy] * my;
        offx[o] = acc[cx] * mx;
    }
}

// ---------------- shared Phase A0 helper ----------------
__device__ inline void bilinear_params(int t, int n, int ho, int wo0,
                                       const float* __restrict__ offy,
                                       const float* __restrict__ offx,
                                       float4* p_w4, int4* p_idx4)
{
    if (t < K2 * TP) {
        int k = t >> 4;
        int p = t & 15;
        int wo = wo0 + p;
        size_t oi = (((size_t)n * K2 + k) * HD + ho) * WD + wo;
        float oy = offy[oi];
        float ox = offx[oi];
        int ki = k / 3, kj = k - ki * 3;
        float py = (float)(ho - 1 + ki) + oy;
        float px = (float)(wo - 1 + kj) + ox;
        float y0f = floorf(py), x0f = floorf(px);
        float wy = py - y0f, wx = px - x0f;
        int y0 = (int)y0f, x0 = (int)x0f;
        float wy0 = 1.f - wy, wx0 = 1.f - wx;

        int y0c = min(max(y0, 0), HD - 1);
        int y1c = min(max(y0 + 1, 0), HD - 1);
        int x0c = min(max(x0, 0), WD - 1);
        int x1c = min(max(x0 + 1, 0), WD - 1);
        bool vy0 = (y0 >= 0) && (y0 < HD);
        bool vy1 = (y0 + 1 >= 0) && (y0 + 1 < HD);
        bool vx0 = (x0 >= 0) && (x0 < WD);
        bool vx1 = (x0 + 1 >= 0) && (x0 + 1 < WD);

        float4 w4;
        w4.x = (vy0 && vx0) ? wy0 * wx0 : 0.f;
        w4.y = (vy0 && vx1) ? wy0 * wx  : 0.f;
        w4.z = (vy1 && vx0) ? wy  * wx0 : 0.f;
        w4.w = (vy1 && vx1) ? wy  * wx  : 0.f;
        int4 i4;
        i4.x = y0c * WD + x0c;
        i4.y = y0c * WD + x1c;
        i4.z = y1c * WD + x0c;
        i4.w = y1c * WD + x1c;
        p_w4[t] = w4;
        p_idx4[t] = i4;
    }
}

// ---------------- Kernel 2 (v2): NHWC coalesced gather + contraction ----------------
// grid: (WD/TP, HD, NB), block 256
__global__ __launch_bounds__(256) void deform2_kernel(
    const float* __restrict__ xT,     // [n][h][w][c]
    const float* __restrict__ offy, const float* __restrict__ offx,
    const float* __restrict__ wt,     // [ck][o]  576 x 64, ck = c*9+k
    const float* __restrict__ bias,
    float* __restrict__ out)
{
    __shared__ __align__(16) float val_s[CK * VROW];   // [r][p] rows padded to 20 floats
    __shared__ float4 p_w4[K2 * TP];
    __shared__ int4   p_idx4[K2 * TP];

    int t = threadIdx.x;
    int wo0 = blockIdx.x * TP;
    int ho  = blockIdx.y;
    int n   = blockIdx.z;

    bilinear_params(t, n, ho, wo0, offy, offx, p_w4, p_idx4);
    __syncthreads();

    // ---- Phase A: one wave per (k,p) task; lane = channel; 4 coalesced loads ----
    int wv = t >> 6;
    int c  = t & 63;
    const float* xTn = xT + (size_t)n * HW * CIN;
    for (int task = wv; task < K2 * TP; task += 4) {
        int k = task >> 4;
        int p = task & 15;
        float4 w4 = p_w4[task];
        int4  i4 = p_idx4[task];
        float g = w4.x * xTn[(size_t)i4.x * CIN + c]
                + w4.y * xTn[(size_t)i4.y * CIN + c]
                + w4.z * xTn[(size_t)i4.z * CIN + c]
                + w4.w * xTn[(size_t)i4.w * CIN + c];
        val_s[(c * 9 + k) * VROW + p] = g;
    }
    __syncthreads();

    // ---- Phase B: out[o][p] = sum_r wt[r][o] * val[r][p] ----
    int o = t & 63;
    int q = t >> 6;       // pixel quad
    float4 acc = {0.f, 0.f, 0.f, 0.f};
    const float* wp = wt + o;
    #pragma unroll 4
    for (int r = 0; r < CK; r++) {
        float w = wp[r * COUT];
        float4 vv = *(const float4*)&val_s[r * VROW + q * 4];
        acc.x += w * vv.x;
        acc.y += w * vv.y;
        acc.z += w * vv.z;
        acc.w += w * vv.w;
    }
    float b = bias[o];
    acc.x += b; acc.y += b; acc.z += b; acc.w += b;

    __syncthreads();                    // done reading val_s
    float* os = val_s;                  // reuse as out staging [o][17]
    os[o * 17 + q * 4 + 0] = acc.x;
    os[o * 17 + q * 4 + 1] = acc.y;
    os[o * 17 + q * 4 + 2] = acc.z;
    os[o * 17 + q * 4 + 3] = acc.w;
    __syncthreads();

    size_t obase = ((size_t)n * COUT) * HW + (size_t)ho * WD + wo0;
    #pragma unroll
    for (int i = 0; i < 4; i++) {
        int l = t + 256 * i;
        int oo = l >> 4;
        int p = l & 15;
        out[obase + (size_t)oo * HW + p] = os[oo * 17 + p];
    }
}

// ---------------- Kernel 2 (v1 fallback, NCHW scattered gather) ----------------
__global__ __launch_bounds__(256) void deform_kernel(
    const float* __restrict__ x,
    const float* __restrict__ offy, const float* __restrict__ offx,
    const float* __restrict__ wt,
    const float* __restrict__ bias,
    float* __restrict__ out)
{
    __shared__ __align__(16) float val_s[CK * TP];
    __shared__ float4 p_w4[K2 * TP];
    __shared__ int4   p_idx4[K2 * TP];

    int t = threadIdx.x;
    int wo0 = blockIdx.x * TP;
    int ho  = blockIdx.y;
    int n   = blockIdx.z;

    bilinear_params(t, n, ho, wo0, offy, offx, p_w4, p_idx4);
    __syncthreads();

    const float* xn = x + (size_t)n * CIN * HW;
    for (int e = t; e < CK * TP; e += 256) {
        int row = e >> 4;
        int p = e & 15;
        int c = row / 9;
        int k = row - c * 9;
        int task = (k << 4) | p;
        float4 w4 = p_w4[task];
        int4  i4 = p_idx4[task];
        const float* xc = xn + (size_t)c * HW;
        float g = w4.x * xc[i4.x] + w4.y * xc[i4.y]
                + w4.z * xc[i4.z] + w4.w * xc[i4.w];
        val_s[e] = g;
    }
    __syncthreads();

    int o = t & 63;
    int q = t >> 6;
    float4 acc = {0.f, 0.f, 0.f, 0.f};
    const float4* v4 = (const float4*)val_s;
    const float* wp = wt + o;
    #pragma unroll 4
    for (int r = 0; r < CK; r++) {
        float w = wp[r * COUT];
        float4 vv = v4[r * 4 + q];
        acc.x += w * vv.x;
        acc.y += w * vv.y;
        acc.z += w * vv.z;
        acc.w += w * vv.w;
    }
    float b = bias[o];
    acc.x += b; acc.y += b; acc.z += b; acc.w += b;

    __syncthreads();
    float4* o4 = (float4*)val_s;
    o4[o * 4 + q] = acc;
    __syncthreads();

    size_t obase = ((size_t)n * COUT) * HW + (size_t)ho * WD + wo0;
    #pragma unroll
    for (int i = 0; i < 4; i++) {
        int l = t + 256 * i;
        int oo = l >> 4;
        int p = l & 15;
        out[obase + (size_t)oo * HW + p] = val_s[l];
    }
}

extern "C" void kernel_launch(void* const* d_in, const int* in_sizes, int n_in,
                              void* d_out, int out_size, void* d_ws, size_t ws_size,
                              hipStream_t stream) {
    const float* x      = (const float*)d_in[0];
    const float* w_off  = (const float*)d_in[1];
    const float* b_off  = (const float*)d_in[2];
    const float* w_mask = (const float*)d_in[3];
    const float* b_mask = (const float*)d_in[4];
    const float* weight = (const float*)d_in[5];
    const float* bias   = (const float*)d_in[6];
    float* out = (float*)d_out;

    // workspace layout (floats): offy | offx | wt | xT
    float* offy = (float*)d_ws;
    float* offx = offy + OFFSZ;
    float* wt   = offx + OFFSZ;
    float* xT   = wt + WTSZ;

    size_t need_v2 = (2 * OFFSZ + WTSZ + XTSZ) * sizeof(float);

    transpose_w_kernel<<<144, 256, 0, stream>>>(weight, wt);
    offmask_kernel<<<256, 256, 0, stream>>>(x, w_off, b_off, w_mask, b_mask, offy, offx);

    if (ws_size >= need_v2) {
        transpose_x_kernel<<<dim3(WD / 64, HD, NB), 256, 0, stream>>>(x, xT);
        deform2_kernel<<<dim3(WD / TP, HD, NB), 256, 0, stream>>>(xT, offy, offx, wt, bias, out);
    } else {
        deform_kernel<<<dim3(WD / TP, HD, NB), 256, 0, stream>>>(x, offy, offx, wt, bias, out);
    }
}

// Round 4
// 204.446 us; speedup vs baseline: 1.7878x; 1.6891x over previous
//
#include <hip/hip_runtime.h>
#include <math.h>

#define HD 128
#define WD 128
#define CIN 64
#define COUT 64
#define NB 4
#define K2 9
#define HW (HD*WD)          // 16384
#define CK 576              // CIN*K2, K of both GEMMs
#define TP 16               // pixels per block
#define NKK 18              // K-steps of 32

#define XTSZ  ((size_t)NB * HW * CIN)    // 4194304 floats (NHWC x)
#define WAM   (4 * NKK * 64 * 8)         // 36864 shorts per main A-frag buffer
#define WAO   (2 * NKK * 64 * 8)         // 18432 shorts per offset A-frag buffer
#define OFFSZ ((size_t)NB * K2 * HW)     // fallback
#define WTSZ  ((size_t)CK * COUT)        // fallback

typedef __attribute__((ext_vector_type(8))) short short8;
typedef __attribute__((ext_vector_type(4))) float f32x4;

__device__ inline unsigned short f2bf(float v) {
    unsigned int u = __float_as_uint(v);
    unsigned int r = u + 0x7fffu + ((u >> 16) & 1u);
    return (unsigned short)(r >> 16);
}
__device__ inline float bf2f(unsigned short b) {
    return __uint_as_float(((unsigned int)b) << 16);
}

// ---------------- transpose x NCHW -> NHWC ----------------
__global__ __launch_bounds__(256) void transpose_x_kernel(const float* __restrict__ x,
                                                          float* __restrict__ xT) {
    __shared__ float tile[64][65];
    int t = threadIdx.x;
    int w0 = blockIdx.x * 64;
    int h  = blockIdx.y;
    int n  = blockIdx.z;
    int g  = t >> 6;
    int wl = t & 63;
    const float* xb = x + ((size_t)n * CIN) * HW + h * WD + w0;
    #pragma unroll
    for (int i = 0; i < 16; i++) {
        int cc = i * 4 + g;
        tile[cc][wl] = xb[(size_t)cc * HW + wl];
    }
    __syncthreads();
    float* xo = xT + ((size_t)n * HW + (size_t)h * WD + w0) * CIN;
    int cl = t & 63;
    #pragma unroll
    for (int i = 0; i < 16; i++) {
        int ww = i * 4 + g;
        xo[(size_t)ww * CIN + cl] = tile[cl][ww];
    }
}

// ---------------- prep: main-weight A-fragments (hi/lo bf16) ----------------
// layout: idx = ((mt*18+kk)*64+lane)*8+jj ; A[o = mt*16+(lane&15)][r = kk*32+(lane>>4)*8+jj]
__global__ __launch_bounds__(256) void prep_waM_kernel(const float* __restrict__ weight,
                                                       short* __restrict__ hi, short* __restrict__ lo) {
    int idx = blockIdx.x * 256 + threadIdx.x;      // 0..36863
    int jj = idx & 7;
    int lane = (idx >> 3) & 63;
    int kk = (idx >> 9) % NKK;
    int mt = (idx >> 9) / NKK;
    int o = mt * 16 + (lane & 15);
    int r = kk * 32 + (lane >> 4) * 8 + jj;
    float w = weight[(size_t)o * CK + r];
    unsigned short h = f2bf(w);
    hi[idx] = (short)h;
    lo[idx] = (short)f2bf(w - bf2f(h));
}

// ---------------- prep: offset/mask-weight A-fragments ----------------
// j = mt*16+(lane&15): j<18 -> w_off ch j ; 18<=j<27 -> w_mask ch j-18 ; else 0
__global__ __launch_bounds__(256) void prep_waO_kernel(const float* __restrict__ w_off,
                                                       const float* __restrict__ w_mask,
                                                       short* __restrict__ hi, short* __restrict__ lo) {
    int idx = blockIdx.x * 256 + threadIdx.x;      // 0..18431
    int jj = idx & 7;
    int lane = (idx >> 3) & 63;
    int kk = (idx >> 9) % NKK;
    int mt = (idx >> 9) / NKK;
    int j = mt * 16 + (lane & 15);
    int r = kk * 32 + (lane >> 4) * 8 + jj;
    int ci = r / 9, tap = r - ci * 9;
    float w = 0.f;
    if (j < 18)      w = w_off[((size_t)j * CIN + ci) * 9 + tap];
    else if (j < 27) w = w_mask[((size_t)(j - 18) * CIN + ci) * 9 + tap];
    unsigned short h = f2bf(w);
    hi[idx] = (short)h;
    lo[idx] = (short)f2bf(w - bf2f(h));
}

// ---------------- fused kernel ----------------
// grid (WD/TP, HD, NB), block 256
__global__ __launch_bounds__(256) void fused_kernel(
    const float* __restrict__ xT,
    const short* __restrict__ waM_hi, const short* __restrict__ waM_lo,
    const short* __restrict__ waO_hi, const short* __restrict__ waO_lo,
    const float* __restrict__ b_off, const float* __restrict__ b_mask,
    const float* __restrict__ bias,
    float* __restrict__ out)
{
    // B-operand buffers: 72 chunks x (16 p x 8 jj) bf16, p slot swizzled by chunk
    __shared__ __align__(16) short val_hi[72 * 128];
    __shared__ __align__(16) short val_lo[72 * 128];
    __shared__ float conv_s[27 * 17];
    __shared__ float4 p_w4[K2 * TP];
    __shared__ int4   p_idx4[K2 * TP];

    int t = threadIdx.x;
    int wv = t >> 6;
    int lane = t & 63;
    int wo0 = blockIdx.x * TP;
    int ho  = blockIdx.y;
    int n   = blockIdx.z;
    const float* xTn = xT + (size_t)n * HW * CIN;
    int c = lane;                      // channel for gather phases
    int p16 = lane & 15, quad = lane >> 4;

    // ---- stage 1: build patch (3x3 conv inputs) in B-frag layout ----
    for (int task = wv; task < K2 * TP; task += 4) {
        int tap = task >> 4, p = task & 15;
        int ti = tap / 3, tj = tap - ti * 3;
        int y = ho - 1 + ti, xx = wo0 + p - 1 + tj;
        float v = 0.f;
        if (y >= 0 && y < HD && xx >= 0 && xx < WD)
            v = xTn[((size_t)y * WD + xx) * CIN + c];
        int r = c * 9 + tap;
        int c2 = r >> 3, jj = r & 7;
        int addr = c2 * 128 + ((p + c2) & 15) * 8 + jj;
        unsigned short h = f2bf(v);
        val_hi[addr] = (short)h;
        val_lo[addr] = (short)f2bf(v - bf2f(h));
    }
    __syncthreads();

    // ---- stage 2: offset/mask conv GEMM (waves 0,1), C[27][16] ----
    if (wv < 2) {
        f32x4 acc = {0.f, 0.f, 0.f, 0.f};
        for (int kk = 0; kk < NKK; kk++) {
            int abase = ((wv * NKK + kk) * 64 + lane) * 8;
            short8 ah = *(const short8*)&waO_hi[abase];
            short8 al = *(const short8*)&waO_lo[abase];
            int c2 = kk * 4 + quad;
            int baddr = c2 * 128 + ((p16 + c2) & 15) * 8;
            short8 bh = *(const short8*)&val_hi[baddr];
            short8 bl = *(const short8*)&val_lo[baddr];
            acc = __builtin_amdgcn_mfma_f32_16x16x32_bf16(ah, bh, acc, 0, 0, 0);
            acc = __builtin_amdgcn_mfma_f32_16x16x32_bf16(ah, bl, acc, 0, 0, 0);
            acc = __builtin_amdgcn_mfma_f32_16x16x32_bf16(al, bh, acc, 0, 0, 0);
        }
        #pragma unroll
        for (int i = 0; i < 4; i++) {
            int j = wv * 16 + quad * 4 + i;
            if (j < 27) {
                float bv = (j < 18) ? b_off[j] : b_mask[j - 18];
                conv_s[j * 17 + p16] = acc[i] + bv;
            }
        }
    }
    __syncthreads();

    // ---- stage 3: sigmoid-modulated offsets -> bilinear params ----
    if (t < K2 * TP) {
        int k = t >> 4, p = t & 15;
        float oy_raw = conv_s[(2 * k) * 17 + p];
        float ox_raw = conv_s[(2 * k + 1) * 17 + p];
        float my = 1.f / (1.f + expf(-conv_s[(18 + (2 * k) % 9) * 17 + p]));
        float mx = 1.f / (1.f + expf(-conv_s[(18 + (2 * k + 1) % 9) * 17 + p]));
        float oy = oy_raw * my;
        float ox = ox_raw * mx;
        int ki = k / 3, kj = k - ki * 3;
        int wo = wo0 + p;
        float py = (float)(ho - 1 + ki) + oy;
        float px = (float)(wo - 1 + kj) + ox;
        float y0f = floorf(py), x0f = floorf(px);
        float wy = py - y0f, wx = px - x0f;
        int y0 = (int)y0f, x0 = (int)x0f;
        float wy0 = 1.f - wy, wx0 = 1.f - wx;
        int y0c = min(max(y0, 0), HD - 1);
        int y1c = min(max(y0 + 1, 0), HD - 1);
        int x0c = min(max(x0, 0), WD - 1);
        int x1c = min(max(x0 + 1, 0), WD - 1);
        bool vy0 = (y0 >= 0) && (y0 < HD);
        bool vy1 = (y0 + 1 >= 0) && (y0 + 1 < HD);
        bool vx0 = (x0 >= 0) && (x0 < WD);
        bool vx1 = (x0 + 1 >= 0) && (x0 + 1 < WD);
        float4 w4;
        w4.x = (vy0 && vx0) ? wy0 * wx0 : 0.f;
        w4.y = (vy0 && vx1) ? wy0 * wx  : 0.f;
        w4.z = (vy1 && vx0) ? wy  * wx0 : 0.f;
        w4.w = (vy1 && vx1) ? wy  * wx  : 0.f;
        int4 i4;
        i4.x = y0c * WD + x0c;
        i4.y = y0c * WD + x1c;
        i4.z = y1c * WD + x0c;
        i4.w = y1c * WD + x1c;
        p_w4[t] = w4;
        p_idx4[t] = i4;
    }
    __syncthreads();

    // ---- stage 4: bilinear gather into B-frag layout (overwrites patch) ----
    for (int task = wv; task < K2 * TP; task += 4) {
        int k = task >> 4, p = task & 15;
        float4 w4 = p_w4[task];
        int4  i4 = p_idx4[task];
        float g = w4.x * xTn[(size_t)i4.x * CIN + c]
                + w4.y * xTn[(size_t)i4.y * CIN + c]
                + w4.z * xTn[(size_t)i4.z * CIN + c]
                + w4.w * xTn[(size_t)i4.w * CIN + c];
        int r = c * 9 + k;
        int c2 = r >> 3, jj = r & 7;
        int addr = c2 * 128 + ((p + c2) & 15) * 8 + jj;
        unsigned short h = f2bf(g);
        val_hi[addr] = (short)h;
        val_lo[addr] = (short)f2bf(g - bf2f(h));
    }
    __syncthreads();

    // ---- stage 5: main GEMM C[64 o][16 p], wave w owns o in [16w,16w+16) ----
    f32x4 acc = {0.f, 0.f, 0.f, 0.f};
    for (int kk = 0; kk < NKK; kk++) {
        int abase = ((wv * NKK + kk) * 64 + lane) * 8;
        short8 ah = *(const short8*)&waM_hi[abase];
        short8 al = *(const short8*)&waM_lo[abase];
        int c2 = kk * 4 + quad;
        int baddr = c2 * 128 + ((p16 + c2) & 15) * 8;
        short8 bh = *(const short8*)&val_hi[baddr];
        short8 bl = *(const short8*)&val_lo[baddr];
        acc = __builtin_amdgcn_mfma_f32_16x16x32_bf16(ah, bh, acc, 0, 0, 0);
        acc = __builtin_amdgcn_mfma_f32_16x16x32_bf16(ah, bl, acc, 0, 0, 0);
        acc = __builtin_amdgcn_mfma_f32_16x16x32_bf16(al, bh, acc, 0, 0, 0);
    }
    __syncthreads();                 // val buffers free for staging
    float* os = (float*)val_hi;      // [o][17]
    #pragma unroll
    for (int i = 0; i < 4; i++) {
        int o = wv * 16 + quad * 4 + i;
        os[o * 17 + p16] = acc[i] + bias[o];
    }
    __syncthreads();

    size_t obase = ((size_t)n * COUT) * HW + (size_t)ho * WD + wo0;
    #pragma unroll
    for (int i = 0; i < 4; i++) {
        int l = t + 256 * i;
        int oo = l >> 4, p = l & 15;
        out[obase + (size_t)oo * HW + p] = os[oo * 17 + p];
    }
}

// ================= fallback path (R1-proven, NCHW) =================
__global__ void transpose_w_kernel(const float* __restrict__ w, float* __restrict__ wt) {
    int i = blockIdx.x * 256 + threadIdx.x;
    int o = i / CK;
    int ck = i - o * CK;
    wt[ck * COUT + o] = w[i];
}

__global__ __launch_bounds__(256) void offmask_kernel(
    const float* __restrict__ x,
    const float* __restrict__ w_off, const float* __restrict__ b_off,
    const float* __restrict__ w_mask, const float* __restrict__ b_mask,
    float* __restrict__ offy, float* __restrict__ offx)
{
    __shared__ float ws[CK][27];
    int t = threadIdx.x;
    for (int i = t; i < CK * 27; i += 256) {
        int j = i % 27;
        int citap = i / 27;
        int ci = citap / 9;
        int tap = citap - ci * 9;
        float v;
        if (j < 18) v = w_off[(j * CIN + ci) * 9 + tap];
        else        v = w_mask[((j - 18) * CIN + ci) * 9 + tap];
        ws[citap][j] = v;
    }
    __syncthreads();

    int pix = blockIdx.x * 256 + t;
    int n  = pix >> 14;
    int ho = (pix >> 7) & 127;
    int wo = pix & 127;

    float acc[27];
    #pragma unroll
    for (int j = 0; j < 18; j++) acc[j] = b_off[j];
    #pragma unroll
    for (int j = 0; j < 9; j++)  acc[18 + j] = b_mask[j];

    int offs[9];
    bool oks[9];
    #pragma unroll
    for (int dy = 0; dy < 3; dy++) {
        int y = ho - 1 + dy;
        #pragma unroll
        for (int dx = 0; dx < 3; dx++) {
            int xx = wo - 1 + dx;
            bool ok = (y >= 0) && (y < HD) && (xx >= 0) && (xx < WD);
            oks[dy * 3 + dx] = ok;
            offs[dy * 3 + dx] = (ok ? y : 0) * WD + (ok ? xx : 0);
        }
    }
    const float* xn = x + (size_t)n * CIN * HW;
    for (int ci = 0; ci < CIN; ci++) {
        const float* xc = xn + (size_t)ci * HW;
        float v[9];
        #pragma unroll
        for (int tap = 0; tap < 9; tap++)
            v[tap] = oks[tap] ? xc[offs[tap]] : 0.f;
        #pragma unroll
        for (int tap = 0; tap < 9; tap++) {
            const float* wrow = ws[ci * 9 + tap];
            float vv = v[tap];
            #pragma unroll
            for (int j = 0; j < 27; j++) acc[j] += wrow[j] * vv;
        }
    }
    float m[9];
    #pragma unroll
    for (int j = 0; j < 9; j++) m[j] = 1.f / (1.f + expf(-acc[18 + j]));
    #pragma unroll
    for (int k = 0; k < 9; k++) {
        int cy = 2 * k, cx = 2 * k + 1;
        float my = m[cy < 9 ? cy : cy - 9];
        float mx = m[cx < 9 ? cx : cx - 9];
        size_t o = (((size_t)n * K2 + k) * HD + ho) * WD + wo;
        offy[o] = acc[cy] * my;
        offx[o] = acc[cx] * mx;
    }
}

__global__ __launch_bounds__(256) void deform_kernel(
    const float* __restrict__ x,
    const float* __restrict__ offy, const float* __restrict__ offx,
    const float* __restrict__ wt,
    const float* __restrict__ bias,
    float* __restrict__ out)
{
    __shared__ __align__(16) float val_s[CK * TP];
    __shared__ float4 p_w4[K2 * TP];
    __shared__ int4   p_idx4[K2 * TP];

    int t = threadIdx.x;
    int wo0 = blockIdx.x * TP;
    int ho  = blockIdx.y;
    int n   = blockIdx.z;

    if (t < K2 * TP) {
        int k = t >> 4, p = t & 15;
        int wo = wo0 + p;
        size_t oi = (((size_t)n * K2 + k) * HD + ho) * WD + wo;
        float oy = offy[oi], ox = offx[oi];
        int ki = k / 3, kj = k - ki * 3;
        float py = (float)(ho - 1 + ki) + oy;
        float px = (float)(wo - 1 + kj) + ox;
        float y0f = floorf(py), x0f = floorf(px);
        float wy = py - y0f, wx = px - x0f;
        int y0 = (int)y0f, x0 = (int)x0f;
        float wy0 = 1.f - wy, wx0 = 1.f - wx;
        int y0c = min(max(y0, 0), HD - 1);
        int y1c = min(max(y0 + 1, 0), HD - 1);
        int x0c = min(max(x0, 0), WD - 1);
        int x1c = min(max(x0 + 1, 0), WD - 1);
        bool vy0 = (y0 >= 0) && (y0 < HD);
        bool vy1 = (y0 + 1 >= 0) && (y0 + 1 < HD);
        bool vx0 = (x0 >= 0) && (x0 < WD);
        bool vx1 = (x0 + 1 >= 0) && (x0 + 1 < WD);
        float4 w4;
        w4.x = (vy0 && vx0) ? wy0 * wx0 : 0.f;
        w4.y = (vy0 && vx1) ? wy0 * wx  : 0.f;
        w4.z = (vy1 && vx0) ? wy  * wx0 : 0.f;
        w4.w = (vy1 && vx1) ? wy  * wx  : 0.f;
        int4 i4;
        i4.x = y0c * WD + x0c;
        i4.y = y0c * WD + x1c;
        i4.z = y1c * WD + x0c;
        i4.w = y1c * WD + x1c;
        p_w4[t] = w4;
        p_idx4[t] = i4;
    }
    __syncthreads();

    const float* xn = x + (size_t)n * CIN * HW;
    for (int e = t; e < CK * TP; e += 256) {
        int row = e >> 4, p = e & 15;
        int cc = row / 9, k = row - cc * 9;
        int task = (k << 4) | p;
        float4 w4 = p_w4[task];
        int4  i4 = p_idx4[task];
        const float* xc = xn + (size_t)cc * HW;
        val_s[e] = w4.x * xc[i4.x] + w4.y * xc[i4.y]
                 + w4.z * xc[i4.z] + w4.w * xc[i4.w];
    }
    __syncthreads();

    int o = t & 63, q = t >> 6;
    float4 acc = {0.f, 0.f, 0.f, 0.f};
    const float4* v4 = (const float4*)val_s;
    const float* wp = wt + o;
    #pragma unroll 4
    for (int r = 0; r < CK; r++) {
        float w = wp[r * COUT];
        float4 vv = v4[r * 4 + q];
        acc.x += w * vv.x; acc.y += w * vv.y;
        acc.z += w * vv.z; acc.w += w * vv.w;
    }
    float b = bias[o];
    acc.x += b; acc.y += b; acc.z += b; acc.w += b;
    __syncthreads();
    float4* o4 = (float4*)val_s;
    o4[o * 4 + q] = acc;
    __syncthreads();
    size_t obase = ((size_t)n * COUT) * HW + (size_t)ho * WD + wo0;
    #pragma unroll
    for (int i = 0; i < 4; i++) {
        int l = t + 256 * i;
        int oo = l >> 4, p = l & 15;
        out[obase + (size_t)oo * HW + p] = val_s[l];
    }
}

extern "C" void kernel_launch(void* const* d_in, const int* in_sizes, int n_in,
                              void* d_out, int out_size, void* d_ws, size_t ws_size,
                              hipStream_t stream) {
    const float* x      = (const float*)d_in[0];
    const float* w_off  = (const float*)d_in[1];
    const float* b_off  = (const float*)d_in[2];
    const float* w_mask = (const float*)d_in[3];
    const float* b_mask = (const float*)d_in[4];
    const float* weight = (const float*)d_in[5];
    const float* bias   = (const float*)d_in[6];
    float* out = (float*)d_out;

    // ws layout: xT (floats) | waM_hi | waM_lo | waO_hi | waO_lo (shorts)
    float* xT = (float*)d_ws;
    short* waM_hi = (short*)(xT + XTSZ);
    short* waM_lo = waM_hi + WAM;
    short* waO_hi = waM_lo + WAM;
    short* waO_lo = waO_hi + WAO;
    size_t need = XTSZ * sizeof(float) + (size_t)(2 * WAM + 2 * WAO) * sizeof(short);

    if (ws_size >= need) {
        prep_waM_kernel<<<WAM / 256, 256, 0, stream>>>(weight, waM_hi, waM_lo);
        prep_waO_kernel<<<WAO / 256, 256, 0, stream>>>(w_off, w_mask, waO_hi, waO_lo);
        transpose_x_kernel<<<dim3(WD / 64, HD, NB), 256, 0, stream>>>(x, xT);
        fused_kernel<<<dim3(WD / TP, HD, NB), 256, 0, stream>>>(
            xT, waM_hi, waM_lo, waO_hi, waO_lo, b_off, b_mask, bias, out);
    } else {
        float* offy = (float*)d_ws;
        float* offx = offy + OFFSZ;
        float* wt   = offx + OFFSZ;
        transpose_w_kernel<<<144, 256, 0, stream>>>(weight, wt);
        offmask_kernel<<<256, 256, 0, stream>>>(x, w_off, b_off, w_mask, b_mask, offy, offx);
        deform_kernel<<<dim3(WD / TP, HD, NB), 256, 0, stream>>>(x, offy, offx, wt, bias, out);
    }
}

// Round 5
// 155.667 us; speedup vs baseline: 2.3480x; 1.3134x over previous
//
#include <hip/hip_runtime.h>
#include <math.h>

#define HD 128
#define WD 128
#define WP 130              // padded width/height (1-halo)
#define CIN 64
#define COUT 64
#define NB 4
#define K2 9
#define HW (HD*WD)          // 16384
#define CK 576              // CIN*K2, K of both GEMMs (k-major permuted: r' = k*64+c)
#define TP 16               // pixels per block
#define NKK 18              // K-steps of 32

#define WAM   (4 * NKK * 64 * 8)             // 36864 shorts per main A-frag buffer
#define WAO   (2 * NKK * 64 * 8)             // 18432 shorts per offset A-frag buffer
#define XTP   ((size_t)NB * WP * WP * CIN)   // 4326400 shorts (padded NHWC bf16 x)
#define OFFSZ ((size_t)NB * K2 * HW)         // fallback
#define WTSZ  ((size_t)CK * COUT)            // fallback

typedef __attribute__((ext_vector_type(8))) short short8;
typedef __attribute__((ext_vector_type(4))) float f32x4;

__device__ inline unsigned short f2bf(float v) {
    unsigned int u = __float_as_uint(v);
    unsigned int r = u + 0x7fffu + ((u >> 16) & 1u);
    return (unsigned short)(r >> 16);
}
__device__ inline float bf2f(unsigned short b) {
    return __uint_as_float(((unsigned int)b) << 16);
}

// ---------------- transpose x NCHW fp32 -> padded NHWC bf16 ----------------
// grid (WD/64, HD, NB), block 256. Border assumed pre-zeroed (memset).
__global__ __launch_bounds__(256) void transpose_xp_kernel(const float* __restrict__ x,
                                                           unsigned short* __restrict__ xp) {
    __shared__ float tile[64][65];
    int t = threadIdx.x;
    int w0 = blockIdx.x * 64;
    int h  = blockIdx.y;
    int n  = blockIdx.z;
    int g  = t >> 6;
    int wl = t & 63;
    const float* xb = x + ((size_t)n * CIN) * HW + h * WD + w0;
    #pragma unroll
    for (int i = 0; i < 16; i++) {
        int cc = i * 4 + g;
        tile[cc][wl] = xb[(size_t)cc * HW + wl];
    }
    __syncthreads();
    size_t rowbase = (((size_t)n * WP + (h + 1)) * WP + (w0 + 1)) * CIN;
    int cl = t & 63;
    #pragma unroll
    for (int i = 0; i < 16; i++) {
        int ww = i * 4 + g;
        xp[rowbase + (size_t)ww * CIN + cl] = f2bf(tile[cl][ww]);
    }
}

// ---------------- prep: main-weight A-fragments (hi/lo bf16, k-major K) ----------------
// idx = ((mt*18+kk)*64+lane)*8+jj ; A[o = mt*16+(lane&15)][r' = kk*32+(lane>>4)*8+jj]
// r' = k*64+c  ->  weight element [o][c][k]
__global__ __launch_bounds__(256) void prep_waM_kernel(const float* __restrict__ weight,
                                                       short* __restrict__ hi, short* __restrict__ lo) {
    int idx = blockIdx.x * 256 + threadIdx.x;      // 0..36863
    int jj = idx & 7;
    int lane = (idx >> 3) & 63;
    int kk = (idx >> 9) % NKK;
    int mt = (idx >> 9) / NKK;
    int o = mt * 16 + (lane & 15);
    int rp = kk * 32 + (lane >> 4) * 8 + jj;
    int k = rp >> 6, c = rp & 63;
    float w = weight[((size_t)o * CIN + c) * 9 + k];
    unsigned short h = f2bf(w);
    hi[idx] = (short)h;
    lo[idx] = (short)f2bf(w - bf2f(h));
}

// ---------------- prep: offset/mask-weight A-fragments (k-major K) ----------------
__global__ __launch_bounds__(256) void prep_waO_kernel(const float* __restrict__ w_off,
                                                       const float* __restrict__ w_mask,
                                                       short* __restrict__ hi, short* __restrict__ lo) {
    int idx = blockIdx.x * 256 + threadIdx.x;      // 0..18431
    int jj = idx & 7;
    int lane = (idx >> 3) & 63;
    int kk = (idx >> 9) % NKK;
    int mt = (idx >> 9) / NKK;
    int j = mt * 16 + (lane & 15);
    int rp = kk * 32 + (lane >> 4) * 8 + jj;
    int k = rp >> 6, c = rp & 63;
    float w = 0.f;
    if (j < 18)      w = w_off[((size_t)j * CIN + c) * 9 + k];
    else if (j < 27) w = w_mask[((size_t)(j - 18) * CIN + c) * 9 + k];
    unsigned short h = f2bf(w);
    hi[idx] = (short)h;
    lo[idx] = (short)f2bf(w - bf2f(h));
}

// ---------------- fused kernel ----------------
// grid (WD/TP, HD, NB), block 256
__global__ __launch_bounds__(256) void fused_kernel(
    const unsigned short* __restrict__ xp,
    const short* __restrict__ waM_hi, const short* __restrict__ waM_lo,
    const short* __restrict__ waO_hi, const short* __restrict__ waO_lo,
    const float* __restrict__ b_off, const float* __restrict__ b_mask,
    const float* __restrict__ bias,
    float* __restrict__ out)
{
    // B operand: 72 chunks x (16 p-slots x 8 jj) bf16, p slot swizzled by chunk.
    // chunk c2 = r'>>3 ; r' = k*64+c (k-major) -> writes contiguous in c = conflict-free
    __shared__ __align__(16) short val_hi[72 * 128];     // 18432 B
    __shared__ float conv_s[27 * 17];
    __shared__ float4 p_w4[K2 * TP];
    __shared__ int4   p_idx4[K2 * TP];                   // pre-multiplied by CIN

    int t = threadIdx.x;
    int wv = t >> 6;
    int lane = t & 63;
    int wo0 = blockIdx.x * TP;
    int ho  = blockIdx.y;
    int n   = blockIdx.z;
    const unsigned short* xpn = xp + (size_t)n * WP * WP * CIN;
    int c = lane;
    int p16 = lane & 15, quad = lane >> 4;

    // ---- stage 1: patch (3x3 conv inputs) -> B-frag layout; raw bf16 copy, no bounds ----
    for (int task = wv; task < K2 * TP; task += 4) {
        int tap = task >> 4, p = task & 15;
        int ti = tap / 3, tj = tap - ti * 3;
        unsigned short v = xpn[((size_t)(ho + ti) * WP + (wo0 + p + tj)) * CIN + c];
        int rp = tap * 64 + c;
        int c2 = rp >> 3, jj = c & 7;
        val_hi[c2 * 128 + ((p + c2) & 15) * 8 + jj] = (short)v;
    }
    __syncthreads();

    // ---- stage 2: offset/mask conv GEMM (waves 0,1), C[27][16], A split hi/lo ----
    if (wv < 2) {
        f32x4 acc = {0.f, 0.f, 0.f, 0.f};
        for (int kk = 0; kk < NKK; kk++) {
            int abase = ((wv * NKK + kk) * 64 + lane) * 8;
            short8 ah = *(const short8*)&waO_hi[abase];
            short8 al = *(const short8*)&waO_lo[abase];
            int c2 = kk * 4 + quad;
            short8 b = *(const short8*)&val_hi[c2 * 128 + ((p16 + c2) & 15) * 8];
            acc = __builtin_amdgcn_mfma_f32_16x16x32_bf16(ah, b, acc, 0, 0, 0);
            acc = __builtin_amdgcn_mfma_f32_16x16x32_bf16(al, b, acc, 0, 0, 0);
        }
        #pragma unroll
        for (int i = 0; i < 4; i++) {
            int j = wv * 16 + quad * 4 + i;
            if (j < 27) {
                float bv = (j < 18) ? b_off[j] : b_mask[j - 18];
                conv_s[j * 17 + p16] = acc[i] + bv;
            }
        }
    }
    __syncthreads();

    // ---- stage 3: sigmoid-modulated offsets -> bilinear params (padded indices) ----
    if (t < K2 * TP) {
        int k = t >> 4, p = t & 15;
        float oy_raw = conv_s[(2 * k) * 17 + p];
        float ox_raw = conv_s[(2 * k + 1) * 17 + p];
        float my = 1.f / (1.f + expf(-conv_s[(18 + (2 * k) % 9) * 17 + p]));
        float mx = 1.f / (1.f + expf(-conv_s[(18 + (2 * k + 1) % 9) * 17 + p]));
        float oy = oy_raw * my;
        float ox = ox_raw * mx;
        int ki = k / 3, kj = k - ki * 3;
        int wo = wo0 + p;
        float py = (float)(ho - 1 + ki) + oy;
        float px = (float)(wo - 1 + kj) + ox;
        float y0f = floorf(py), x0f = floorf(px);
        float wy = py - y0f, wx = px - x0f;
        int y0 = (int)y0f, x0 = (int)x0f;
        float wy0 = 1.f - wy, wx0 = 1.f - wx;
        int y0c = min(max(y0, 0), HD - 1);
        int y1c = min(max(y0 + 1, 0), HD - 1);
        int x0c = min(max(x0, 0), WD - 1);
        int x1c = min(max(x0 + 1, 0), WD - 1);
        bool vy0 = (y0 >= 0) && (y0 < HD);
        bool vy1 = (y0 + 1 >= 0) && (y0 + 1 < HD);
        bool vx0 = (x0 >= 0) && (x0 < WD);
        bool vx1 = (x0 + 1 >= 0) && (x0 + 1 < WD);
        float4 w4;
        w4.x = (vy0 && vx0) ? wy0 * wx0 : 0.f;
        w4.y = (vy0 && vx1) ? wy0 * wx  : 0.f;
        w4.z = (vy1 && vx0) ? wy  * wx0 : 0.f;
        w4.w = (vy1 && vx1) ? wy  * wx  : 0.f;
        int4 i4;
        i4.x = ((y0c + 1) * WP + (x0c + 1)) * CIN;
        i4.y = ((y0c + 1) * WP + (x1c + 1)) * CIN;
        i4.z = ((y1c + 1) * WP + (x0c + 1)) * CIN;
        i4.w = ((y1c + 1) * WP + (x1c + 1)) * CIN;
        p_w4[t] = w4;
        p_idx4[t] = i4;
    }
    __syncthreads();

    // ---- stage 4: bilinear gather -> B-frag layout (overwrites patch) ----
    for (int task = wv; task < K2 * TP; task += 4) {
        int k = task >> 4, p = task & 15;
        float4 w4 = p_w4[task];
        int4  i4 = p_idx4[task];
        float g = w4.x * bf2f(xpn[i4.x + c])
                + w4.y * bf2f(xpn[i4.y + c])
                + w4.z * bf2f(xpn[i4.z + c])
                + w4.w * bf2f(xpn[i4.w + c]);
        int rp = k * 64 + c;
        int c2 = rp >> 3, jj = c & 7;
        val_hi[c2 * 128 + ((p + c2) & 15) * 8 + jj] = (short)f2bf(g);
    }
    __syncthreads();

    // ---- stage 5: main GEMM C[64 o][16 p], wave w owns o in [16w,16w+16) ----
    f32x4 acc = {0.f, 0.f, 0.f, 0.f};
    for (int kk = 0; kk < NKK; kk++) {
        int abase = ((wv * NKK + kk) * 64 + lane) * 8;
        short8 ah = *(const short8*)&waM_hi[abase];
        short8 al = *(const short8*)&waM_lo[abase];
        int c2 = kk * 4 + quad;
        short8 b = *(const short8*)&val_hi[c2 * 128 + ((p16 + c2) & 15) * 8];
        acc = __builtin_amdgcn_mfma_f32_16x16x32_bf16(ah, b, acc, 0, 0, 0);
        acc = __builtin_amdgcn_mfma_f32_16x16x32_bf16(al, b, acc, 0, 0, 0);
    }
    __syncthreads();                 // val buffer free for staging
    float* os = (float*)val_hi;      // [o][17]
    #pragma unroll
    for (int i = 0; i < 4; i++) {
        int o = wv * 16 + quad * 4 + i;
        os[o * 17 + p16] = acc[i] + bias[o];
    }
    __syncthreads();

    size_t obase = ((size_t)n * COUT) * HW + (size_t)ho * WD + wo0;
    #pragma unroll
    for (int i = 0; i < 4; i++) {
        int l = t + 256 * i;
        int oo = l >> 4, p = l & 15;
        out[obase + (size_t)oo * HW + p] = os[oo * 17 + p];
    }
}

// ================= fallback path (R1-proven, fp32 NCHW) =================
__global__ void transpose_w_kernel(const float* __restrict__ w, float* __restrict__ wt) {
    int i = blockIdx.x * 256 + threadIdx.x;
    int o = i / CK;
    int ck = i - o * CK;
    wt[ck * COUT + o] = w[i];
}

__global__ __launch_bounds__(256) void offmask_kernel(
    const float* __restrict__ x,
    const float* __restrict__ w_off, const float* __restrict__ b_off,
    const float* __restrict__ w_mask, const float* __restrict__ b_mask,
    float* __restrict__ offy, float* __restrict__ offx)
{
    __shared__ float ws[CK][27];
    int t = threadIdx.x;
    for (int i = t; i < CK * 27; i += 256) {
        int j = i % 27;
        int citap = i / 27;
        int ci = citap / 9;
        int tap = citap - ci * 9;
        float v;
        if (j < 18) v = w_off[(j * CIN + ci) * 9 + tap];
        else        v = w_mask[((j - 18) * CIN + ci) * 9 + tap];
        ws[citap][j] = v;
    }
    __syncthreads();

    int pix = blockIdx.x * 256 + t;
    int n  = pix >> 14;
    int ho = (pix >> 7) & 127;
    int wo = pix & 127;

    float acc[27];
    #pragma unroll
    for (int j = 0; j < 18; j++) acc[j] = b_off[j];
    #pragma unroll
    for (int j = 0; j < 9; j++)  acc[18 + j] = b_mask[j];

    int offs[9];
    bool oks[9];
    #pragma unroll
    for (int dy = 0; dy < 3; dy++) {
        int y = ho - 1 + dy;
        #pragma unroll
        for (int dx = 0; dx < 3; dx++) {
            int xx = wo - 1 + dx;
            bool ok = (y >= 0) && (y < HD) && (xx >= 0) && (xx < WD);
            oks[dy * 3 + dx] = ok;
            offs[dy * 3 + dx] = (ok ? y : 0) * WD + (ok ? xx : 0);
        }
    }
    const float* xn = x + (size_t)n * CIN * HW;
    for (int ci = 0; ci < CIN; ci++) {
        const float* xc = xn + (size_t)ci * HW;
        float v[9];
        #pragma unroll
        for (int tap = 0; tap < 9; tap++)
            v[tap] = oks[tap] ? xc[offs[tap]] : 0.f;
        #pragma unroll
        for (int tap = 0; tap < 9; tap++) {
            const float* wrow = ws[ci * 9 + tap];
            float vv = v[tap];
            #pragma unroll
            for (int j = 0; j < 27; j++) acc[j] += wrow[j] * vv;
        }
    }
    float m[9];
    #pragma unroll
    for (int j = 0; j < 9; j++) m[j] = 1.f / (1.f + expf(-acc[18 + j]));
    #pragma unroll
    for (int k = 0; k < 9; k++) {
        int cy = 2 * k, cx = 2 * k + 1;
        float my = m[cy < 9 ? cy : cy - 9];
        float mx = m[cx < 9 ? cx : cx - 9];
        size_t o = (((size_t)n * K2 + k) * HD + ho) * WD + wo;
        offy[o] = acc[cy] * my;
        offx[o] = acc[cx] * mx;
    }
}

__global__ __launch_bounds__(256) void deform_kernel(
    const float* __restrict__ x,
    const float* __restrict__ offy, const float* __restrict__ offx,
    const float* __restrict__ wt,
    const float* __restrict__ bias,
    float* __restrict__ out)
{
    __shared__ __align__(16) float val_s[CK * TP];
    __shared__ float4 p_w4[K2 * TP];
    __shared__ int4   p_idx4[K2 * TP];

    int t = threadIdx.x;
    int wo0 = blockIdx.x * TP;
    int ho  = blockIdx.y;
    int n   = blockIdx.z;

    if (t < K2 * TP) {
        int k = t >> 4, p = t & 15;
        int wo = wo0 + p;
        size_t oi = (((size_t)n * K2 + k) * HD + ho) * WD + wo;
        float oy = offy[oi], ox = offx[oi];
        int ki = k / 3, kj = k - ki * 3;
        float py = (float)(ho - 1 + ki) + oy;
        float px = (float)(wo - 1 + kj) + ox;
        float y0f = floorf(py), x0f = floorf(px);
        float wy = py - y0f, wx = px - x0f;
        int y0 = (int)y0f, x0 = (int)x0f;
        float wy0 = 1.f - wy, wx0 = 1.f - wx;
        int y0c = min(max(y0, 0), HD - 1);
        int y1c = min(max(y0 + 1, 0), HD - 1);
        int x0c = min(max(x0, 0), WD - 1);
        int x1c = min(max(x0 + 1, 0), WD - 1);
        bool vy0 = (y0 >= 0) && (y0 < HD);
        bool vy1 = (y0 + 1 >= 0) && (y0 + 1 < HD);
        bool vx0 = (x0 >= 0) && (x0 < WD);
        bool vx1 = (x0 + 1 >= 0) && (x0 + 1 < WD);
        float4 w4;
        w4.x = (vy0 && vx0) ? wy0 * wx0 : 0.f;
        w4.y = (vy0 && vx1) ? wy0 * wx  : 0.f;
        w4.z = (vy1 && vx0) ? wy  * wx0 : 0.f;
        w4.w = (vy1 && vx1) ? wy  * wx  : 0.f;
        int4 i4;
        i4.x = y0c * WD + x0c;
        i4.y = y0c * WD + x1c;
        i4.z = y1c * WD + x0c;
        i4.w = y1c * WD + x1c;
        p_w4[t] = w4;
        p_idx4[t] = i4;
    }
    __syncthreads();

    const float* xn = x + (size_t)n * CIN * HW;
    for (int e = t; e < CK * TP; e += 256) {
        int row = e >> 4, p = e & 15;
        int cc = row / 9, k = row - cc * 9;
        int task = (k << 4) | p;
        float4 w4 = p_w4[task];
        int4  i4 = p_idx4[task];
        const float* xc = xn + (size_t)cc * HW;
        val_s[e] = w4.x * xc[i4.x] + w4.y * xc[i4.y]
                 + w4.z * xc[i4.z] + w4.w * xc[i4.w];
    }
    __syncthreads();

    int o = t & 63, q = t >> 6;
    float4 acc = {0.f, 0.f, 0.f, 0.f};
    const float4* v4 = (const float4*)val_s;
    const float* wp = wt + o;
    #pragma unroll 4
    for (int r = 0; r < CK; r++) {
        float w = wp[r * COUT];
        float4 vv = v4[r * 4 + q];
        acc.x += w * vv.x; acc.y += w * vv.y;
        acc.z += w * vv.z; acc.w += w * vv.w;
    }
    float b = bias[o];
    acc.x += b; acc.y += b; acc.z += b; acc.w += b;
    __syncthreads();
    float4* o4 = (float4*)val_s;
    o4[o * 4 + q] = acc;
    __syncthreads();
    size_t obase = ((size_t)n * COUT) * HW + (size_t)ho * WD + wo0;
    #pragma unroll
    for (int i = 0; i < 4; i++) {
        int l = t + 256 * i;
        int oo = l >> 4, p = l & 15;
        out[obase + (size_t)oo * HW + p] = val_s[l];
    }
}

extern "C" void kernel_launch(void* const* d_in, const int* in_sizes, int n_in,
                              void* d_out, int out_size, void* d_ws, size_t ws_size,
                              hipStream_t stream) {
    const float* x      = (const float*)d_in[0];
    const float* w_off  = (const float*)d_in[1];
    const float* b_off  = (const float*)d_in[2];
    const float* w_mask = (const float*)d_in[3];
    const float* b_mask = (const float*)d_in[4];
    const float* weight = (const float*)d_in[5];
    const float* bias   = (const float*)d_in[6];
    float* out = (float*)d_out;

    // ws layout (shorts): waM_hi | waM_lo | waO_hi | waO_lo | xp (padded bf16 NHWC)
    short* base = (short*)d_ws;
    short* waM_hi = base;
    short* waM_lo = waM_hi + WAM;
    short* waO_hi = waM_lo + WAM;
    short* waO_lo = waO_hi + WAO;
    unsigned short* xp = (unsigned short*)(waO_lo + WAO);
    size_t need = ((size_t)2 * WAM + 2 * WAO + XTP) * sizeof(short);

    if (ws_size >= need) {
        hipMemsetAsync(xp, 0, XTP * sizeof(short), stream);   // zero halo
        prep_waM_kernel<<<WAM / 256, 256, 0, stream>>>(weight, waM_hi, waM_lo);
        prep_waO_kernel<<<WAO / 256, 256, 0, stream>>>(w_off, w_mask, waO_hi, waO_lo);
        transpose_xp_kernel<<<dim3(WD / 64, HD, NB), 256, 0, stream>>>(x, xp);
        fused_kernel<<<dim3(WD / TP, HD, NB), 256, 0, stream>>>(
            xp, waM_hi, waM_lo, waO_hi, waO_lo, b_off, b_mask, bias, out);
    } else {
        float* offy = (float*)d_ws;
        float* offx = offy + OFFSZ;
        float* wt   = offx + OFFSZ;
        transpose_w_kernel<<<144, 256, 0, stream>>>(weight, wt);
        offmask_kernel<<<256, 256, 0, stream>>>(x, w_off, b_off, w_mask, b_mask, offy, offx);
        deform_kernel<<<dim3(WD / TP, HD, NB), 256, 0, stream>>>(x, offy, offx, wt, bias, out);
    }
}

// Round 6
// 140.842 us; speedup vs baseline: 2.5952x; 1.1053x over previous
//
#include <hip/hip_runtime.h>
#include <math.h>

#define HD 128
#define WD 128
#define WP 130              // padded width/height (1-halo)
#define CIN 64
#define COUT 64
#define NB 4
#define K2 9
#define HW (HD*WD)          // 16384
#define CK 576              // CIN*K2, K of both GEMMs (k-major permuted: r' = k*64+c)
#define TP 16               // pixels per block
#define NKK 18              // K-steps of 32

#define WAM   (4 * NKK * 64 * 8)             // 36864 shorts per main A-frag buffer
#define WAO   (2 * NKK * 64 * 8)             // 18432 shorts per offset A-frag buffer
#define XTP   ((size_t)NB * WP * WP * CIN)   // 4326400 shorts (padded NHWC bf16 x)
#define OFFSZ ((size_t)NB * K2 * HW)         // fallback
#define WTSZ  ((size_t)CK * COUT)            // fallback

typedef __attribute__((ext_vector_type(8))) short short8;
typedef __attribute__((ext_vector_type(4))) float f32x4;

__device__ inline unsigned short f2bf(float v) {
    unsigned int u = __float_as_uint(v);
    unsigned int r = u + 0x7fffu + ((u >> 16) & 1u);
    return (unsigned short)(r >> 16);
}
__device__ inline float bf2f(unsigned short b) {
    return __uint_as_float(((unsigned int)b) << 16);
}
// pack two f32 -> two bf16 (lo = a, hi = b)
__device__ inline unsigned int pack_bf16(float a, float b) {
#if __has_builtin(__builtin_amdgcn_cvt_pk_bf16_f32)
    auto r = __builtin_amdgcn_cvt_pk_bf16_f32(a, b);
    unsigned int u; __builtin_memcpy(&u, &r, 4); return u;
#else
    return ((unsigned int)f2bf(b) << 16) | (unsigned int)f2bf(a);
#endif
}

// ---------------- transpose x NCHW fp32 -> padded NHWC bf16 ----------------
// grid (WD/64, HD, NB), block 256. Border assumed pre-zeroed (memset).
__global__ __launch_bounds__(256) void transpose_xp_kernel(const float* __restrict__ x,
                                                           unsigned short* __restrict__ xp) {
    __shared__ float tile[64][65];
    int t = threadIdx.x;
    int w0 = blockIdx.x * 64;
    int h  = blockIdx.y;
    int n  = blockIdx.z;
    int g  = t >> 6;
    int wl = t & 63;
    const float* xb = x + ((size_t)n * CIN) * HW + h * WD + w0;
    #pragma unroll
    for (int i = 0; i < 16; i++) {
        int cc = i * 4 + g;
        tile[cc][wl] = xb[(size_t)cc * HW + wl];
    }
    __syncthreads();
    size_t rowbase = (((size_t)n * WP + (h + 1)) * WP + (w0 + 1)) * CIN;
    #pragma unroll
    for (int i = 0; i < 8; i++) {
        int u = i * 256 + t;          // 0..2047
        int ww = u >> 5;              // 0..63
        int cp = (u & 31) * 2;        // even channel
        unsigned int r = pack_bf16(tile[cp][ww], tile[cp + 1][ww]);
        *(unsigned int*)&xp[rowbase + (size_t)ww * CIN + cp] = r;
    }
}

// ---------------- prep (merged): A-fragments for main + offset weights ----------------
// blocks [0,144): waM ; [144,216): waO. k-major K: r' = k*64+c.
__global__ __launch_bounds__(256) void prep_wa_kernel(const float* __restrict__ weight,
                                                      const float* __restrict__ w_off,
                                                      const float* __restrict__ w_mask,
                                                      short* __restrict__ mhi, short* __restrict__ mlo,
                                                      short* __restrict__ ohi, short* __restrict__ olo) {
    int gid = blockIdx.x * 256 + threadIdx.x;
    if (gid < WAM) {
        int idx = gid;
        int jj = idx & 7;
        int lane = (idx >> 3) & 63;
        int kk = (idx >> 9) % NKK;
        int mt = (idx >> 9) / NKK;
        int o = mt * 16 + (lane & 15);
        int rp = kk * 32 + (lane >> 4) * 8 + jj;
        int k = rp >> 6, c = rp & 63;
        float w = weight[((size_t)o * CIN + c) * 9 + k];
        unsigned short h = f2bf(w);
        mhi[idx] = (short)h;
        mlo[idx] = (short)f2bf(w - bf2f(h));
    } else {
        int idx = gid - WAM;           // 0..18431
        int jj = idx & 7;
        int lane = (idx >> 3) & 63;
        int kk = (idx >> 9) % NKK;
        int mt = (idx >> 9) / NKK;
        int j = mt * 16 + (lane & 15);
        int rp = kk * 32 + (lane >> 4) * 8 + jj;
        int k = rp >> 6, c = rp & 63;
        float w = 0.f;
        if (j < 18)      w = w_off[((size_t)j * CIN + c) * 9 + k];
        else if (j < 27) w = w_mask[((size_t)(j - 18) * CIN + c) * 9 + k];
        unsigned short h = f2bf(w);
        ohi[idx] = (short)h;
        olo[idx] = (short)f2bf(w - bf2f(h));
    }
}

// ---------------- fused kernel ----------------
// grid (WD/TP, HD, NB), block 256
__global__ __launch_bounds__(256) void fused_kernel(
    const unsigned short* __restrict__ xp,
    const short* __restrict__ waM_hi, const short* __restrict__ waM_lo,
    const short* __restrict__ waO_hi, const short* __restrict__ waO_lo,
    const float* __restrict__ b_off, const float* __restrict__ b_mask,
    const float* __restrict__ bias,
    float* __restrict__ out)
{
    // B operand: 72 chunks x (16 p-slots x 8 jj) bf16, p slot swizzled by chunk.
    __shared__ __align__(16) short val_hi[72 * 128];     // 18432 B
    __shared__ float conv_s[27 * 17];
    __shared__ float4 p_w4[K2 * TP];
    __shared__ int4   p_idx4[K2 * TP];                   // pre-multiplied by CIN

    int t = threadIdx.x;
    int wv = t >> 6;
    int lane = t & 63;
    int wo0 = blockIdx.x * TP;
    int ho  = blockIdx.y;
    int n   = blockIdx.z;
    const unsigned short* xpn = xp + (size_t)n * WP * WP * CIN;
    int p16 = lane & 15, quad = lane >> 4;

    // ---- stage 1: patch -> B-frag layout; pure 16B copies (bf16, no bounds) ----
    // unit u = tap*128 + p*8 + g : load 8 channels (8g..8g+7), one ds_write_b128
    #pragma unroll
    for (int i = 0; i < 5; i++) {
        int u = t + 256 * i;
        if (u < K2 * TP * 8) {
            int tap = u >> 7;
            int p = (u >> 3) & 15;
            int g = u & 7;
            int ti = tap / 3, tj = tap - ti * 3;
            const short8 v = *(const short8*)&xpn[((size_t)(ho + ti) * WP + (wo0 + p + tj)) * CIN + g * 8];
            int c2 = tap * 8 + g;
            *(short8*)&val_hi[c2 * 128 + ((p + c2) & 15) * 8] = v;
        }
    }
    __syncthreads();

    // ---- stage 2: offset/mask conv GEMM (waves 0,1), C[27][16], A split hi/lo ----
    if (wv < 2) {
        f32x4 acc = {0.f, 0.f, 0.f, 0.f};
        for (int kk = 0; kk < NKK; kk++) {
            int abase = ((wv * NKK + kk) * 64 + lane) * 8;
            short8 ah = *(const short8*)&waO_hi[abase];
            short8 al = *(const short8*)&waO_lo[abase];
            int c2 = kk * 4 + quad;
            short8 b = *(const short8*)&val_hi[c2 * 128 + ((p16 + c2) & 15) * 8];
            acc = __builtin_amdgcn_mfma_f32_16x16x32_bf16(ah, b, acc, 0, 0, 0);
            acc = __builtin_amdgcn_mfma_f32_16x16x32_bf16(al, b, acc, 0, 0, 0);
        }
        #pragma unroll
        for (int i = 0; i < 4; i++) {
            int j = wv * 16 + quad * 4 + i;
            if (j < 27) {
                float bv = (j < 18) ? b_off[j] : b_mask[j - 18];
                conv_s[j * 17 + p16] = acc[i] + bv;
            }
        }
    }
    __syncthreads();

    // ---- stage 3: sigmoid-modulated offsets -> bilinear params (padded indices) ----
    if (t < K2 * TP) {
        int k = t >> 4, p = t & 15;
        float oy_raw = conv_s[(2 * k) * 17 + p];
        float ox_raw = conv_s[(2 * k + 1) * 17 + p];
        float my = 1.f / (1.f + expf(-conv_s[(18 + (2 * k) % 9) * 17 + p]));
        float mx = 1.f / (1.f + expf(-conv_s[(18 + (2 * k + 1) % 9) * 17 + p]));
        float oy = oy_raw * my;
        float ox = ox_raw * mx;
        int ki = k / 3, kj = k - ki * 3;
        int wo = wo0 + p;
        float py = (float)(ho - 1 + ki) + oy;
        float px = (float)(wo - 1 + kj) + ox;
        float y0f = floorf(py), x0f = floorf(px);
        float wy = py - y0f, wx = px - x0f;
        int y0 = (int)y0f, x0 = (int)x0f;
        float wy0 = 1.f - wy, wx0 = 1.f - wx;
        int y0c = min(max(y0, 0), HD - 1);
        int y1c = min(max(y0 + 1, 0), HD - 1);
        int x0c = min(max(x0, 0), WD - 1);
        int x1c = min(max(x0 + 1, 0), WD - 1);
        bool vy0 = (y0 >= 0) && (y0 < HD);
        bool vy1 = (y0 + 1 >= 0) && (y0 + 1 < HD);
        bool vx0 = (x0 >= 0) && (x0 < WD);
        bool vx1 = (x0 + 1 >= 0) && (x0 + 1 < WD);
        float4 w4;
        w4.x = (vy0 && vx0) ? wy0 * wx0 : 0.f;
        w4.y = (vy0 && vx1) ? wy0 * wx  : 0.f;
        w4.z = (vy1 && vx0) ? wy  * wx0 : 0.f;
        w4.w = (vy1 && vx1) ? wy  * wx  : 0.f;
        int4 i4;
        i4.x = ((y0c + 1) * WP + (x0c + 1)) * CIN;
        i4.y = ((y0c + 1) * WP + (x1c + 1)) * CIN;
        i4.z = ((y1c + 1) * WP + (x0c + 1)) * CIN;
        i4.w = ((y1c + 1) * WP + (x1c + 1)) * CIN;
        p_w4[t] = w4;
        p_idx4[t] = i4;
    }
    __syncthreads();

    // ---- stage 4: bilinear gather, 4 channels/lane -> ds_write_b64 ----
    {
        int sub = lane >> 4;           // 0..3
        int c0 = (lane & 15) * 4;      // channel base
        #pragma unroll
        for (int i = 0; i < 9; i++) {
            int task = i * 16 + wv * 4 + sub;
            int k = task >> 4, p = task & 15;
            float4 w4 = p_w4[task];
            int4  i4 = p_idx4[task];
            uint2 qa = *(const uint2*)&xpn[i4.x + c0];
            uint2 qb = *(const uint2*)&xpn[i4.y + c0];
            uint2 qc = *(const uint2*)&xpn[i4.z + c0];
            uint2 qd = *(const uint2*)&xpn[i4.w + c0];
            float g0 = w4.x * __uint_as_float(qa.x << 16)
                     + w4.y * __uint_as_float(qb.x << 16)
                     + w4.z * __uint_as_float(qc.x << 16)
                     + w4.w * __uint_as_float(qd.x << 16);
            float g1 = w4.x * __uint_as_float(qa.x & 0xffff0000u)
                     + w4.y * __uint_as_float(qb.x & 0xffff0000u)
                     + w4.z * __uint_as_float(qc.x & 0xffff0000u)
                     + w4.w * __uint_as_float(qd.x & 0xffff0000u);
            float g2 = w4.x * __uint_as_float(qa.y << 16)
                     + w4.y * __uint_as_float(qb.y << 16)
                     + w4.z * __uint_as_float(qc.y << 16)
                     + w4.w * __uint_as_float(qd.y << 16);
            float g3 = w4.x * __uint_as_float(qa.y & 0xffff0000u)
                     + w4.y * __uint_as_float(qb.y & 0xffff0000u)
                     + w4.z * __uint_as_float(qc.y & 0xffff0000u)
                     + w4.w * __uint_as_float(qd.y & 0xffff0000u);
            uint2 r;
            r.x = pack_bf16(g0, g1);
            r.y = pack_bf16(g2, g3);
            int c2 = k * 8 + (c0 >> 3);
            int jj = c0 & 7;           // 0 or 4
            *(uint2*)&val_hi[c2 * 128 + ((p + c2) & 15) * 8 + jj] = r;
        }
    }
    __syncthreads();

    // ---- stage 5: main GEMM C[64 o][16 p], wave w owns o in [16w,16w+16) ----
    f32x4 acc = {0.f, 0.f, 0.f, 0.f};
    for (int kk = 0; kk < NKK; kk++) {
        int abase = ((wv * NKK + kk) * 64 + lane) * 8;
        short8 ah = *(const short8*)&waM_hi[abase];
        short8 al = *(const short8*)&waM_lo[abase];
        int c2 = kk * 4 + quad;
        short8 b = *(const short8*)&val_hi[c2 * 128 + ((p16 + c2) & 15) * 8];
        acc = __builtin_amdgcn_mfma_f32_16x16x32_bf16(ah, b, acc, 0, 0, 0);
        acc = __builtin_amdgcn_mfma_f32_16x16x32_bf16(al, b, acc, 0, 0, 0);
    }
    __syncthreads();                 // val buffer free for staging
    float* os = (float*)val_hi;      // [o][17]
    #pragma unroll
    for (int i = 0; i < 4; i++) {
        int o = wv * 16 + quad * 4 + i;
        os[o * 17 + p16] = acc[i] + bias[o];
    }
    __syncthreads();

    size_t obase = ((size_t)n * COUT) * HW + (size_t)ho * WD + wo0;
    #pragma unroll
    for (int i = 0; i < 4; i++) {
        int l = t + 256 * i;
        int oo = l >> 4, p = l & 15;
        out[obase + (size_t)oo * HW + p] = os[oo * 17 + p];
    }
}

// ================= fallback path (R1-proven, fp32 NCHW) =================
__global__ void transpose_w_kernel(const float* __restrict__ w, float* __restrict__ wt) {
    int i = blockIdx.x * 256 + threadIdx.x;
    int o = i / CK;
    int ck = i - o * CK;
    wt[ck * COUT + o] = w[i];
}

__global__ __launch_bounds__(256) void offmask_kernel(
    const float* __restrict__ x,
    const float* __restrict__ w_off, const float* __restrict__ b_off,
    const float* __restrict__ w_mask, const float* __restrict__ b_mask,
    float* __restrict__ offy, float* __restrict__ offx)
{
    __shared__ float ws[CK][27];
    int t = threadIdx.x;
    for (int i = t; i < CK * 27; i += 256) {
        int j = i % 27;
        int citap = i / 27;
        int ci = citap / 9;
        int tap = citap - ci * 9;
        float v;
        if (j < 18) v = w_off[(j * CIN + ci) * 9 + tap];
        else        v = w_mask[((j - 18) * CIN + ci) * 9 + tap];
        ws[citap][j] = v;
    }
    __syncthreads();

    int pix = blockIdx.x * 256 + t;
    int n  = pix >> 14;
    int ho = (pix >> 7) & 127;
    int wo = pix & 127;

    float acc[27];
    #pragma unroll
    for (int j = 0; j < 18; j++) acc[j] = b_off[j];
    #pragma unroll
    for (int j = 0; j < 9; j++)  acc[18 + j] = b_mask[j];

    int offs[9];
    bool oks[9];
    #pragma unroll
    for (int dy = 0; dy < 3; dy++) {
        int y = ho - 1 + dy;
        #pragma unroll
        for (int dx = 0; dx < 3; dx++) {
            int xx = wo - 1 + dx;
            bool ok = (y >= 0) && (y < HD) && (xx >= 0) && (xx < WD);
            oks[dy * 3 + dx] = ok;
            offs[dy * 3 + dx] = (ok ? y : 0) * WD + (ok ? xx : 0);
        }
    }
    const float* xn = x + (size_t)n * CIN * HW;
    for (int ci = 0; ci < CIN; ci++) {
        const float* xc = xn + (size_t)ci * HW;
        float v[9];
        #pragma unroll
        for (int tap = 0; tap < 9; tap++)
            v[tap] = oks[tap] ? xc[offs[tap]] : 0.f;
        #pragma unroll
        for (int tap = 0; tap < 9; tap++) {
            const float* wrow = ws[ci * 9 + tap];
            float vv = v[tap];
            #pragma unroll
            for (int j = 0; j < 27; j++) acc[j] += wrow[j] * vv;
        }
    }
    float m[9];
    #pragma unroll
    for (int j = 0; j < 9; j++) m[j] = 1.f / (1.f + expf(-acc[18 + j]));
    #pragma unroll
    for (int k = 0; k < 9; k++) {
        int cy = 2 * k, cx = 2 * k + 1;
        float my = m[cy < 9 ? cy : cy - 9];
        float mx = m[cx < 9 ? cx : cx - 9];
        size_t o = (((size_t)n * K2 + k) * HD + ho) * WD + wo;
        offy[o] = acc[cy] * my;
        offx[o] = acc[cx] * mx;
    }
}

__global__ __launch_bounds__(256) void deform_kernel(
    const float* __restrict__ x,
    const float* __restrict__ offy, const float* __restrict__ offx,
    const float* __restrict__ wt,
    const float* __restrict__ bias,
    float* __restrict__ out)
{
    __shared__ __align__(16) float val_s[CK * TP];
    __shared__ float4 p_w4[K2 * TP];
    __shared__ int4   p_idx4[K2 * TP];

    int t = threadIdx.x;
    int wo0 = blockIdx.x * TP;
    int ho  = blockIdx.y;
    int n   = blockIdx.z;

    if (t < K2 * TP) {
        int k = t >> 4, p = t & 15;
        int wo = wo0 + p;
        size_t oi = (((size_t)n * K2 + k) * HD + ho) * WD + wo;
        float oy = offy[oi], ox = offx[oi];
        int ki = k / 3, kj = k - ki * 3;
        float py = (float)(ho - 1 + ki) + oy;
        float px = (float)(wo - 1 + kj) + ox;
        float y0f = floorf(py), x0f = floorf(px);
        float wy = py - y0f, wx = px - x0f;
        int y0 = (int)y0f, x0 = (int)x0f;
        float wy0 = 1.f - wy, wx0 = 1.f - wx;
        int y0c = min(max(y0, 0), HD - 1);
        int y1c = min(max(y0 + 1, 0), HD - 1);
        int x0c = min(max(x0, 0), WD - 1);
        int x1c = min(max(x0 + 1, 0), WD - 1);
        bool vy0 = (y0 >= 0) && (y0 < HD);
        bool vy1 = (y0 + 1 >= 0) && (y0 + 1 < HD);
        bool vx0 = (x0 >= 0) && (x0 < WD);
        bool vx1 = (x0 + 1 >= 0) && (x0 + 1 < WD);
        float4 w4;
        w4.x = (vy0 && vx0) ? wy0 * wx0 : 0.f;
        w4.y = (vy0 && vx1) ? wy0 * wx  : 0.f;
        w4.z = (vy1 && vx0) ? wy  * wx0 : 0.f;
        w4.w = (vy1 && vx1) ? wy  * wx  : 0.f;
        int4 i4;
        i4.x = y0c * WD + x0c;
        i4.y = y0c * WD + x1c;
        i4.z = y1c * WD + x0c;
        i4.w = y1c * WD + x1c;
        p_w4[t] = w4;
        p_idx4[t] = i4;
    }
    __syncthreads();

    const float* xn = x + (size_t)n * CIN * HW;
    for (int e = t; e < CK * TP; e += 256) {
        int row = e >> 4, p = e & 15;
        int cc = row / 9, k = row - cc * 9;
        int task = (k << 4) | p;
        float4 w4 = p_w4[task];
        int4  i4 = p_idx4[task];
        const float* xc = xn + (size_t)cc * HW;
        val_s[e] = w4.x * xc[i4.x] + w4.y * xc[i4.y]
                 + w4.z * xc[i4.z] + w4.w * xc[i4.w];
    }
    __syncthreads();

    int o = t & 63, q = t >> 6;
    float4 acc = {0.f, 0.f, 0.f, 0.f};
    const float4* v4 = (const float4*)val_s;
    const float* wp = wt + o;
    #pragma unroll 4
    for (int r = 0; r < CK; r++) {
        float w = wp[r * COUT];
        float4 vv = v4[r * 4 + q];
        acc.x += w * vv.x; acc.y += w * vv.y;
        acc.z += w * vv.z; acc.w += w * vv.w;
    }
    float b = bias[o];
    acc.x += b; acc.y += b; acc.z += b; acc.w += b;
    __syncthreads();
    float4* o4 = (float4*)val_s;
    o4[o * 4 + q] = acc;
    __syncthreads();
    size_t obase = ((size_t)n * COUT) * HW + (size_t)ho * WD + wo0;
    #pragma unroll
    for (int i = 0; i < 4; i++) {
        int l = t + 256 * i;
        int oo = l >> 4, p = l & 15;
        out[obase + (size_t)oo * HW + p] = val_s[l];
    }
}

extern "C" void kernel_launch(void* const* d_in, const int* in_sizes, int n_in,
                              void* d_out, int out_size, void* d_ws, size_t ws_size,
                              hipStream_t stream) {
    const float* x      = (const float*)d_in[0];
    const float* w_off  = (const float*)d_in[1];
    const float* b_off  = (const float*)d_in[2];
    const float* w_mask = (const float*)d_in[3];
    const float* b_mask = (const float*)d_in[4];
    const float* weight = (const float*)d_in[5];
    const float* bias   = (const float*)d_in[6];
    float* out = (float*)d_out;

    // ws layout (shorts): waM_hi | waM_lo | waO_hi | waO_lo | xp (padded bf16 NHWC)
    short* base = (short*)d_ws;
    short* waM_hi = base;
    short* waM_lo = waM_hi + WAM;
    short* waO_hi = waM_lo + WAM;
    short* waO_lo = waO_hi + WAO;
    unsigned short* xp = (unsigned short*)(waO_lo + WAO);
    size_t need = ((size_t)2 * WAM + 2 * WAO + XTP) * sizeof(short);

    if (ws_size >= need) {
        hipMemsetAsync(xp, 0, XTP * sizeof(short), stream);   // zero halo
        prep_wa_kernel<<<(WAM + WAO) / 256, 256, 0, stream>>>(
            weight, w_off, w_mask, waM_hi, waM_lo, waO_hi, waO_lo);
        transpose_xp_kernel<<<dim3(WD / 64, HD, NB), 256, 0, stream>>>(x, xp);
        fused_kernel<<<dim3(WD / TP, HD, NB), 256, 0, stream>>>(
            xp, waM_hi, waM_lo, waO_hi, waO_lo, b_off, b_mask, bias, out);
    } else {
        float* offy = (float*)d_ws;
        float* offx = offy + OFFSZ;
        float* wt   = offx + OFFSZ;
        transpose_w_kernel<<<144, 256, 0, stream>>>(weight, wt);
        offmask_kernel<<<256, 256, 0, stream>>>(x, w_off, b_off, w_mask, b_mask, offy, offx);
        deform_kernel<<<dim3(WD / TP, HD, NB), 256, 0, stream>>>(x, offy, offx, wt, bias, out);
    }
}

// Round 7
// 134.825 us; speedup vs baseline: 2.7110x; 1.0446x over previous
//
#include <hip/hip_runtime.h>
#include <math.h>

#define HD 128
#define WD 128
#define WP 130              // padded width/height (1-halo)
#define CIN 64
#define COUT 64
#define NB 4
#define K2 9
#define HW (HD*WD)          // 16384
#define CK 576              // CIN*K2, K of both GEMMs (k-major permuted: r' = k*64+c)
#define TP 16               // pixels per block
#define NKK 18              // K-steps of 32

#define WAM   (4 * NKK * 64 * 8)             // 36864 shorts per main A-frag buffer
#define WAO   (2 * NKK * 64 * 8)             // 18432 shorts per offset A-frag buffer
#define XTP   ((size_t)NB * WP * WP * CIN)   // 4326400 shorts (padded NHWC bf16 x)
#define OFFSZ ((size_t)NB * K2 * HW)         // fallback
#define WTSZ  ((size_t)CK * COUT)            // fallback

// pre_kernel block partition
#define PRE_T 1024                            // transpose blocks
#define PRE_H 65                              // halo-zero blocks
#define PRE_P ((WAM + WAO) / 256)             // 216 prep blocks
#define HALO_PER_N 33024                      // halo shorts per image
#define HALO_W8 16512                         // total 8-short zero units

typedef __attribute__((ext_vector_type(8))) short short8;
typedef __attribute__((ext_vector_type(4))) float f32x4;

__device__ inline unsigned short f2bf(float v) {
    unsigned int u = __float_as_uint(v);
    unsigned int r = u + 0x7fffu + ((u >> 16) & 1u);
    return (unsigned short)(r >> 16);
}
__device__ inline float bf2f(unsigned short b) {
    return __uint_as_float(((unsigned int)b) << 16);
}
// pack two f32 -> two bf16 (lo = a, hi = b)
__device__ inline unsigned int pack_bf16(float a, float b) {
#if __has_builtin(__builtin_amdgcn_cvt_pk_bf16_f32)
    auto r = __builtin_amdgcn_cvt_pk_bf16_f32(a, b);
    unsigned int u; __builtin_memcpy(&u, &r, 4); return u;
#else
    return ((unsigned int)f2bf(b) << 16) | (unsigned int)f2bf(a);
#endif
}

// ---------------- merged pre-kernel: transpose | halo zero | weight prep ----------------
// grid = PRE_T + PRE_H + PRE_P blocks, 256 threads
__global__ __launch_bounds__(256) void pre_kernel(
    const float* __restrict__ x,
    const float* __restrict__ weight,
    const float* __restrict__ w_off,
    const float* __restrict__ w_mask,
    unsigned short* __restrict__ xp,
    short* __restrict__ mhi, short* __restrict__ mlo,
    short* __restrict__ ohi, short* __restrict__ olo)
{
    __shared__ float tile[64][66];   // [w][c], pad 66
    int bid = blockIdx.x;
    int t = threadIdx.x;

    if (bid < PRE_T) {
        // ---- transpose x NCHW fp32 -> padded NHWC bf16 (64w x 64c tile) ----
        int half = bid & 1;
        int h = (bid >> 1) & 127;
        int n = bid >> 8;
        int w0 = half * 64;
        int g = t >> 6, wl = t & 63;            // g = wave id (uniform per wave)
        const float* xb = x + ((size_t)n * CIN) * HW + h * WD + w0;
        #pragma unroll
        for (int i = 0; i < 16; i++) {
            int cc = i * 4 + g;
            tile[wl][cc] = xb[(size_t)cc * HW + wl];   // coalesced 256B loads, stride-66 LDS writes (2-way)
        }
        __syncthreads();
        size_t rowbase = (((size_t)n * WP + (h + 1)) * WP + (w0 + 1)) * CIN;
        #pragma unroll
        for (int i = 0; i < 8; i++) {
            int u = i * 256 + t;
            int ww = u >> 5;
            int cp = (u & 31) * 2;
            float2 v = *(const float2*)&tile[ww][cp];  // one b64 read, consecutive channels
            *(unsigned int*)&xp[rowbase + (size_t)ww * CIN + cp] = pack_bf16(v.x, v.y);
        }
    } else if (bid < PRE_T + PRE_H) {
        // ---- zero the 1-pixel halo of xp ----
        int widx = (bid - PRE_T) * 256 + t;
        if (widx < HALO_W8) {
            int s = widx * 8;
            int n = s / HALO_PER_N;
            int v = s - n * HALO_PER_N;
            size_t nb = (size_t)n * WP * WP * CIN;
            size_t base;
            if (v < 8320) {                       // h = 0 full row
                base = nb + v;
            } else if (v < 16640) {               // h = 129 full row
                base = nb + (size_t)129 * WP * CIN + (v - 8320);
            } else if (v < 24832) {               // w = 0 strip, h = 1..128
                int v2 = v - 16640; int h = 1 + (v2 >> 6); int c = v2 & 63;
                base = nb + (size_t)h * WP * CIN + c;
            } else {                              // w = 129 strip, h = 1..128
                int v3 = v - 24832; int h = 1 + (v3 >> 6); int c = v3 & 63;
                base = nb + ((size_t)h * WP + 129) * CIN + c;
            }
            short8 z = {0, 0, 0, 0, 0, 0, 0, 0};
            *(short8*)&xp[base] = z;
        }
    } else {
        // ---- weight prep: A-fragments (hi/lo bf16, k-major K: r' = k*64+c) ----
        int gid = (bid - PRE_T - PRE_H) * 256 + t;
        if (gid < WAM) {
            int idx = gid;
            int jj = idx & 7;
            int lane = (idx >> 3) & 63;
            int kk = (idx >> 9) % NKK;
            int mt = (idx >> 9) / NKK;
            int o = mt * 16 + (lane & 15);
            int rp = kk * 32 + (lane >> 4) * 8 + jj;
            int k = rp >> 6, c = rp & 63;
            float w = weight[((size_t)o * CIN + c) * 9 + k];
            unsigned short h = f2bf(w);
            mhi[idx] = (short)h;
            mlo[idx] = (short)f2bf(w - bf2f(h));
        } else {
            int idx = gid - WAM;           // 0..18431
            int jj = idx & 7;
            int lane = (idx >> 3) & 63;
            int kk = (idx >> 9) % NKK;
            int mt = (idx >> 9) / NKK;
            int j = mt * 16 + (lane & 15);
            int rp = kk * 32 + (lane >> 4) * 8 + jj;
            int k = rp >> 6, c = rp & 63;
            float w = 0.f;
            if (j < 18)      w = w_off[((size_t)j * CIN + c) * 9 + k];
            else if (j < 27) w = w_mask[((size_t)(j - 18) * CIN + c) * 9 + k];
            unsigned short h = f2bf(w);
            ohi[idx] = (short)h;
            olo[idx] = (short)f2bf(w - bf2f(h));
        }
    }
}

// ---------------- fused kernel (unchanged from R6) ----------------
// grid (WD/TP, HD, NB), block 256
__global__ __launch_bounds__(256) void fused_kernel(
    const unsigned short* __restrict__ xp,
    const short* __restrict__ waM_hi, const short* __restrict__ waM_lo,
    const short* __restrict__ waO_hi, const short* __restrict__ waO_lo,
    const float* __restrict__ b_off, const float* __restrict__ b_mask,
    const float* __restrict__ bias,
    float* __restrict__ out)
{
    __shared__ __align__(16) short val_hi[72 * 128];     // 18432 B
    __shared__ float conv_s[27 * 17];
    __shared__ float4 p_w4[K2 * TP];
    __shared__ int4   p_idx4[K2 * TP];                   // pre-multiplied by CIN

    int t = threadIdx.x;
    int wv = t >> 6;
    int lane = t & 63;
    int wo0 = blockIdx.x * TP;
    int ho  = blockIdx.y;
    int n   = blockIdx.z;
    const unsigned short* xpn = xp + (size_t)n * WP * WP * CIN;
    int p16 = lane & 15, quad = lane >> 4;

    // ---- stage 1: patch -> B-frag layout; pure 16B copies ----
    #pragma unroll
    for (int i = 0; i < 5; i++) {
        int u = t + 256 * i;
        if (u < K2 * TP * 8) {
            int tap = u >> 7;
            int p = (u >> 3) & 15;
            int g = u & 7;
            int ti = tap / 3, tj = tap - ti * 3;
            const short8 v = *(const short8*)&xpn[((size_t)(ho + ti) * WP + (wo0 + p + tj)) * CIN + g * 8];
            int c2 = tap * 8 + g;
            *(short8*)&val_hi[c2 * 128 + ((p + c2) & 15) * 8] = v;
        }
    }
    __syncthreads();

    // ---- stage 2: offset/mask conv GEMM (waves 0,1), C[27][16], A split hi/lo ----
    if (wv < 2) {
        f32x4 acc = {0.f, 0.f, 0.f, 0.f};
        for (int kk = 0; kk < NKK; kk++) {
            int abase = ((wv * NKK + kk) * 64 + lane) * 8;
            short8 ah = *(const short8*)&waO_hi[abase];
            short8 al = *(const short8*)&waO_lo[abase];
            int c2 = kk * 4 + quad;
            short8 b = *(const short8*)&val_hi[c2 * 128 + ((p16 + c2) & 15) * 8];
            acc = __builtin_amdgcn_mfma_f32_16x16x32_bf16(ah, b, acc, 0, 0, 0);
            acc = __builtin_amdgcn_mfma_f32_16x16x32_bf16(al, b, acc, 0, 0, 0);
        }
        #pragma unroll
        for (int i = 0; i < 4; i++) {
            int j = wv * 16 + quad * 4 + i;
            if (j < 27) {
                float bv = (j < 18) ? b_off[j] : b_mask[j - 18];
                conv_s[j * 17 + p16] = acc[i] + bv;
            }
        }
    }
    __syncthreads();

    // ---- stage 3: sigmoid-modulated offsets -> bilinear params (padded indices) ----
    if (t < K2 * TP) {
        int k = t >> 4, p = t & 15;
        float oy_raw = conv_s[(2 * k) * 17 + p];
        float ox_raw = conv_s[(2 * k + 1) * 17 + p];
        float my = 1.f / (1.f + expf(-conv_s[(18 + (2 * k) % 9) * 17 + p]));
        float mx = 1.f / (1.f + expf(-conv_s[(18 + (2 * k + 1) % 9) * 17 + p]));
        float oy = oy_raw * my;
        float ox = ox_raw * mx;
        int ki = k / 3, kj = k - ki * 3;
        int wo = wo0 + p;
        float py = (float)(ho - 1 + ki) + oy;
        float px = (float)(wo - 1 + kj) + ox;
        float y0f = floorf(py), x0f = floorf(px);
        float wy = py - y0f, wx = px - x0f;
        int y0 = (int)y0f, x0 = (int)x0f;
        float wy0 = 1.f - wy, wx0 = 1.f - wx;
        int y0c = min(max(y0, 0), HD - 1);
        int y1c = min(max(y0 + 1, 0), HD - 1);
        int x0c = min(max(x0, 0), WD - 1);
        int x1c = min(max(x0 + 1, 0), WD - 1);
        bool vy0 = (y0 >= 0) && (y0 < HD);
        bool vy1 = (y0 + 1 >= 0) && (y0 + 1 < HD);
        bool vx0 = (x0 >= 0) && (x0 < WD);
        bool vx1 = (x0 + 1 >= 0) && (x0 + 1 < WD);
        float4 w4;
        w4.x = (vy0 && vx0) ? wy0 * wx0 : 0.f;
        w4.y = (vy0 && vx1) ? wy0 * wx  : 0.f;
        w4.z = (vy1 && vx0) ? wy  * wx0 : 0.f;
        w4.w = (vy1 && vx1) ? wy  * wx  : 0.f;
        int4 i4;
        i4.x = ((y0c + 1) * WP + (x0c + 1)) * CIN;
        i4.y = ((y0c + 1) * WP + (x1c + 1)) * CIN;
        i4.z = ((y1c + 1) * WP + (x0c + 1)) * CIN;
        i4.w = ((y1c + 1) * WP + (x1c + 1)) * CIN;
        p_w4[t] = w4;
        p_idx4[t] = i4;
    }
    __syncthreads();

    // ---- stage 4: bilinear gather, 4 channels/lane -> ds_write_b64 ----
    {
        int sub = lane >> 4;           // 0..3
        int c0 = (lane & 15) * 4;      // channel base
        #pragma unroll
        for (int i = 0; i < 9; i++) {
            int task = i * 16 + wv * 4 + sub;
            int k = task >> 4, p = task & 15;
            float4 w4 = p_w4[task];
            int4  i4 = p_idx4[task];
            uint2 qa = *(const uint2*)&xpn[i4.x + c0];
            uint2 qb = *(const uint2*)&xpn[i4.y + c0];
            uint2 qc = *(const uint2*)&xpn[i4.z + c0];
            uint2 qd = *(const uint2*)&xpn[i4.w + c0];
            float g0 = w4.x * __uint_as_float(qa.x << 16)
                     + w4.y * __uint_as_float(qb.x << 16)
                     + w4.z * __uint_as_float(qc.x << 16)
                     + w4.w * __uint_as_float(qd.x << 16);
            float g1 = w4.x * __uint_as_float(qa.x & 0xffff0000u)
                     + w4.y * __uint_as_float(qb.x & 0xffff0000u)
                     + w4.z * __uint_as_float(qc.x & 0xffff0000u)
                     + w4.w * __uint_as_float(qd.x & 0xffff0000u);
            float g2 = w4.x * __uint_as_float(qa.y << 16)
                     + w4.y * __uint_as_float(qb.y << 16)
                     + w4.z * __uint_as_float(qc.y << 16)
                     + w4.w * __uint_as_float(qd.y << 16);
            float g3 = w4.x * __uint_as_float(qa.y & 0xffff0000u)
                     + w4.y * __uint_as_float(qb.y & 0xffff0000u)
                     + w4.z * __uint_as_float(qc.y & 0xffff0000u)
                     + w4.w * __uint_as_float(qd.y & 0xffff0000u);
            uint2 r;
            r.x = pack_bf16(g0, g1);
            r.y = pack_bf16(g2, g3);
            int c2 = k * 8 + (c0 >> 3);
            int jj = c0 & 7;           // 0 or 4
            *(uint2*)&val_hi[c2 * 128 + ((p + c2) & 15) * 8 + jj] = r;
        }
    }
    __syncthreads();

    // ---- stage 5: main GEMM C[64 o][16 p], wave w owns o in [16w,16w+16) ----
    f32x4 acc = {0.f, 0.f, 0.f, 0.f};
    for (int kk = 0; kk < NKK; kk++) {
        int abase = ((wv * NKK + kk) * 64 + lane) * 8;
        short8 ah = *(const short8*)&waM_hi[abase];
        short8 al = *(const short8*)&waM_lo[abase];
        int c2 = kk * 4 + quad;
        short8 b = *(const short8*)&val_hi[c2 * 128 + ((p16 + c2) & 15) * 8];
        acc = __builtin_amdgcn_mfma_f32_16x16x32_bf16(ah, b, acc, 0, 0, 0);
        acc = __builtin_amdgcn_mfma_f32_16x16x32_bf16(al, b, acc, 0, 0, 0);
    }
    __syncthreads();                 // val buffer free for staging
    float* os = (float*)val_hi;      // [o][17]
    #pragma unroll
    for (int i = 0; i < 4; i++) {
        int o = wv * 16 + quad * 4 + i;
        os[o * 17 + p16] = acc[i] + bias[o];
    }
    __syncthreads();

    size_t obase = ((size_t)n * COUT) * HW + (size_t)ho * WD + wo0;
    #pragma unroll
    for (int i = 0; i < 4; i++) {
        int l = t + 256 * i;
        int oo = l >> 4, p = l & 15;
        out[obase + (size_t)oo * HW + p] = os[oo * 17 + p];
    }
}

// ================= fallback path (R1-proven, fp32 NCHW) =================
__global__ void transpose_w_kernel(const float* __restrict__ w, float* __restrict__ wt) {
    int i = blockIdx.x * 256 + threadIdx.x;
    int o = i / CK;
    int ck = i - o * CK;
    wt[ck * COUT + o] = w[i];
}

__global__ __launch_bounds__(256) void offmask_kernel(
    const float* __restrict__ x,
    const float* __restrict__ w_off, const float* __restrict__ b_off,
    const float* __restrict__ w_mask, const float* __restrict__ b_mask,
    float* __restrict__ offy, float* __restrict__ offx)
{
    __shared__ float ws[CK][27];
    int t = threadIdx.x;
    for (int i = t; i < CK * 27; i += 256) {
        int j = i % 27;
        int citap = i / 27;
        int ci = citap / 9;
        int tap = citap - ci * 9;
        float v;
        if (j < 18) v = w_off[(j * CIN + ci) * 9 + tap];
        else        v = w_mask[((j - 18) * CIN + ci) * 9 + tap];
        ws[citap][j] = v;
    }
    __syncthreads();

    int pix = blockIdx.x * 256 + t;
    int n  = pix >> 14;
    int ho = (pix >> 7) & 127;
    int wo = pix & 127;

    float acc[27];
    #pragma unroll
    for (int j = 0; j < 18; j++) acc[j] = b_off[j];
    #pragma unroll
    for (int j = 0; j < 9; j++)  acc[18 + j] = b_mask[j];

    int offs[9];
    bool oks[9];
    #pragma unroll
    for (int dy = 0; dy < 3; dy++) {
        int y = ho - 1 + dy;
        #pragma unroll
        for (int dx = 0; dx < 3; dx++) {
            int xx = wo - 1 + dx;
            bool ok = (y >= 0) && (y < HD) && (xx >= 0) && (xx < WD);
            oks[dy * 3 + dx] = ok;
            offs[dy * 3 + dx] = (ok ? y : 0) * WD + (ok ? xx : 0);
        }
    }
    const float* xn = x + (size_t)n * CIN * HW;
    for (int ci = 0; ci < CIN; ci++) {
        const float* xc = xn + (size_t)ci * HW;
        float v[9];
        #pragma unroll
        for (int tap = 0; tap < 9; tap++)
            v[tap] = oks[tap] ? xc[offs[tap]] : 0.f;
        #pragma unroll
        for (int tap = 0; tap < 9; tap++) {
            const float* wrow = ws[ci * 9 + tap];
            float vv = v[tap];
            #pragma unroll
            for (int j = 0; j < 27; j++) acc[j] += wrow[j] * vv;
        }
    }
    float m[9];
    #pragma unroll
    for (int j = 0; j < 9; j++) m[j] = 1.f / (1.f + expf(-acc[18 + j]));
    #pragma unroll
    for (int k = 0; k < 9; k++) {
        int cy = 2 * k, cx = 2 * k + 1;
        float my = m[cy < 9 ? cy : cy - 9];
        float mx = m[cx < 9 ? cx : cx - 9];
        size_t o = (((size_t)n * K2 + k) * HD + ho) * WD + wo;
        offy[o] = acc[cy] * my;
        offx[o] = acc[cx] * mx;
    }
}

__global__ __launch_bounds__(256) void deform_kernel(
    const float* __restrict__ x,
    const float* __restrict__ offy, const float* __restrict__ offx,
    const float* __restrict__ wt,
    const float* __restrict__ bias,
    float* __restrict__ out)
{
    __shared__ __align__(16) float val_s[CK * TP];
    __shared__ float4 p_w4[K2 * TP];
    __shared__ int4   p_idx4[K2 * TP];

    int t = threadIdx.x;
    int wo0 = blockIdx.x * TP;
    int ho  = blockIdx.y;
    int n   = blockIdx.z;

    if (t < K2 * TP) {
        int k = t >> 4, p = t & 15;
        int wo = wo0 + p;
        size_t oi = (((size_t)n * K2 + k) * HD + ho) * WD + wo;
        float oy = offy[oi], ox = offx[oi];
        int ki = k / 3, kj = k - ki * 3;
        float py = (float)(ho - 1 + ki) + oy;
        float px = (float)(wo - 1 + kj) + ox;
        float y0f = floorf(py), x0f = floorf(px);
        float wy = py - y0f, wx = px - x0f;
        int y0 = (int)y0f, x0 = (int)x0f;
        float wy0 = 1.f - wy, wx0 = 1.f - wx;
        int y0c = min(max(y0, 0), HD - 1);
        int y1c = min(max(y0 + 1, 0), HD - 1);
        int x0c = min(max(x0, 0), WD - 1);
        int x1c = min(max(x0 + 1, 0), WD - 1);
        bool vy0 = (y0 >= 0) && (y0 < HD);
        bool vy1 = (y0 + 1 >= 0) && (y0 + 1 < HD);
        bool vx0 = (x0 >= 0) && (x0 < WD);
        bool vx1 = (x0 + 1 >= 0) && (x0 + 1 < WD);
        float4 w4;
        w4.x = (vy0 && vx0) ? wy0 * wx0 : 0.f;
        w4.y = (vy0 && vx1) ? wy0 * wx  : 0.f;
        w4.z = (vy1 && vx0) ? wy  * wx0 : 0.f;
        w4.w = (vy1 && vx1) ? wy  * wx  : 0.f;
        int4 i4;
        i4.x = y0c * WD + x0c;
        i4.y = y0c * WD + x1c;
        i4.z = y1c * WD + x0c;
        i4.w = y1c * WD + x1c;
        p_w4[t] = w4;
        p_idx4[t] = i4;
    }
    __syncthreads();

    const float* xn = x + (size_t)n * CIN * HW;
    for (int e = t; e < CK * TP; e += 256) {
        int row = e >> 4, p = e & 15;
        int cc = row / 9, k = row - cc * 9;
        int task = (k << 4) | p;
        float4 w4 = p_w4[task];
        int4  i4 = p_idx4[task];
        const float* xc = xn + (size_t)cc * HW;
        val_s[e] = w4.x * xc[i4.x] + w4.y * xc[i4.y]
                 + w4.z * xc[i4.z] + w4.w * xc[i4.w];
    }
    __syncthreads();

    int o = t & 63, q = t >> 6;
    float4 acc = {0.f, 0.f, 0.f, 0.f};
    const float4* v4 = (const float4*)val_s;
    const float* wp = wt + o;
    #pragma unroll 4
    for (int r = 0; r < CK; r++) {
        float w = wp[r * COUT];
        float4 vv = v4[r * 4 + q];
        acc.x += w * vv.x; acc.y += w * vv.y;
        acc.z += w * vv.z; acc.w += w * vv.w;
    }
    float b = bias[o];
    acc.x += b; acc.y += b; acc.z += b; acc.w += b;
    __syncthreads();
    float4* o4 = (float4*)val_s;
    o4[o * 4 + q] = acc;
    __syncthreads();
    size_t obase = ((size_t)n * COUT) * HW + (size_t)ho * WD + wo0;
    #pragma unroll
    for (int i = 0; i < 4; i++) {
        int l = t + 256 * i;
        int oo = l >> 4, p = l & 15;
        out[obase + (size_t)oo * HW + p] = val_s[l];
    }
}

extern "C" void kernel_launch(void* const* d_in, const int* in_sizes, int n_in,
                              void* d_out, int out_size, void* d_ws, size_t ws_size,
                              hipStream_t stream) {
    const float* x      = (const float*)d_in[0];
    const float* w_off  = (const float*)d_in[1];
    const float* b_off  = (const float*)d_in[2];
    const float* w_mask = (const float*)d_in[3];
    const float* b_mask = (const float*)d_in[4];
    const float* weight = (const float*)d_in[5];
    const float* bias   = (const float*)d_in[6];
    float* out = (float*)d_out;

    // ws layout (shorts): waM_hi | waM_lo | waO_hi | waO_lo | xp (padded bf16 NHWC)
    short* base = (short*)d_ws;
    short* waM_hi = base;
    short* waM_lo = waM_hi + WAM;
    short* waO_hi = waM_lo + WAM;
    short* waO_lo = waO_hi + WAO;
    unsigned short* xp = (unsigned short*)(waO_lo + WAO);
    size_t need = ((size_t)2 * WAM + 2 * WAO + XTP) * sizeof(short);

    if (ws_size >= need) {
        pre_kernel<<<PRE_T + PRE_H + PRE_P, 256, 0, stream>>>(
            x, weight, w_off, w_mask, xp, waM_hi, waM_lo, waO_hi, waO_lo);
        fused_kernel<<<dim3(WD / TP, HD, NB), 256, 0, stream>>>(
            xp, waM_hi, waM_lo, waO_hi, waO_lo, b_off, b_mask, bias, out);
    } else {
        float* offy = (float*)d_ws;
        float* offx = offy + OFFSZ;
        float* wt   = offx + OFFSZ;
        transpose_w_kernel<<<144, 256, 0, stream>>>(weight, wt);
        offmask_kernel<<<256, 256, 0, stream>>>(x, w_off, b_off, w_mask, b_mask, offy, offx);
        deform_kernel<<<dim3(WD / TP, HD, NB), 256, 0, stream>>>(x, offy, offx, wt, bias, out);
    }
}

// Round 8
// 128.674 us; speedup vs baseline: 2.8406x; 1.0478x over previous
//
#include <hip/hip_runtime.h>
#include <math.h>

#define HD 128
#define WD 128
#define WP 130              // padded width/height (1-halo)
#define CIN 64
#define COUT 64
#define NB 4
#define K2 9
#define HW (HD*WD)          // 16384
#define CK 576              // CIN*K2, K of both GEMMs (k-major permuted: r' = k*64+c)
#define TP 16               // pixels per block
#define NKK 18              // K-steps of 32

#define WAM   (4 * NKK * 64 * 8)             // 36864 shorts per main A-frag buffer
#define WAO   (2 * NKK * 64 * 8)             // 18432 shorts per offset A-frag buffer
#define XTP   ((size_t)NB * WP * WP * CIN)   // 4326400 shorts (padded NHWC bf16 x)
#define OFFSZ ((size_t)NB * K2 * HW)         // fallback
#define WTSZ  ((size_t)CK * COUT)            // fallback

// pre_kernel block partition
#define PRE_T 1024                            // transpose blocks
#define PRE_H 65                              // halo-zero blocks
#define PRE_P ((WAM + WAO) / 256)             // 216 prep blocks
#define HALO_PER_N 33024                      // halo shorts per image
#define HALO_W8 16512                         // total 8-short zero units

typedef __attribute__((ext_vector_type(8))) short short8;
typedef __attribute__((ext_vector_type(4))) float f32x4;

__device__ inline unsigned short f2bf(float v) {
    unsigned int u = __float_as_uint(v);
    unsigned int r = u + 0x7fffu + ((u >> 16) & 1u);
    return (unsigned short)(r >> 16);
}
__device__ inline float bf2f(unsigned short b) {
    return __uint_as_float(((unsigned int)b) << 16);
}
// pack two f32 -> two bf16 (lo = a, hi = b)
__device__ inline unsigned int pack_bf16(float a, float b) {
#if __has_builtin(__builtin_amdgcn_cvt_pk_bf16_f32)
    auto r = __builtin_amdgcn_cvt_pk_bf16_f32(a, b);
    unsigned int u; __builtin_memcpy(&u, &r, 4); return u;
#else
    return ((unsigned int)f2bf(b) << 16) | (unsigned int)f2bf(a);
#endif
}

// ---------------- merged pre-kernel: transpose | halo zero | weight prep ----------------
__global__ __launch_bounds__(256) void pre_kernel(
    const float* __restrict__ x,
    const float* __restrict__ weight,
    const float* __restrict__ w_off,
    const float* __restrict__ w_mask,
    unsigned short* __restrict__ xp,
    short* __restrict__ mhi, short* __restrict__ mlo,
    short* __restrict__ ohi, short* __restrict__ olo)
{
    __shared__ float tile[64][66];   // [w][c], pad 66
    int bid = blockIdx.x;
    int t = threadIdx.x;

    if (bid < PRE_T) {
        int half = bid & 1;
        int h = (bid >> 1) & 127;
        int n = bid >> 8;
        int w0 = half * 64;
        int g = t >> 6, wl = t & 63;
        const float* xb = x + ((size_t)n * CIN) * HW + h * WD + w0;
        #pragma unroll
        for (int i = 0; i < 16; i++) {
            int cc = i * 4 + g;
            tile[wl][cc] = xb[(size_t)cc * HW + wl];
        }
        __syncthreads();
        size_t rowbase = (((size_t)n * WP + (h + 1)) * WP + (w0 + 1)) * CIN;
        #pragma unroll
        for (int i = 0; i < 8; i++) {
            int u = i * 256 + t;
            int ww = u >> 5;
            int cp = (u & 31) * 2;
            float2 v = *(const float2*)&tile[ww][cp];
            *(unsigned int*)&xp[rowbase + (size_t)ww * CIN + cp] = pack_bf16(v.x, v.y);
        }
    } else if (bid < PRE_T + PRE_H) {
        int widx = (bid - PRE_T) * 256 + t;
        if (widx < HALO_W8) {
            int s = widx * 8;
            int n = s / HALO_PER_N;
            int v = s - n * HALO_PER_N;
            size_t nb = (size_t)n * WP * WP * CIN;
            size_t base;
            if (v < 8320) {
                base = nb + v;
            } else if (v < 16640) {
                base = nb + (size_t)129 * WP * CIN + (v - 8320);
            } else if (v < 24832) {
                int v2 = v - 16640; int h = 1 + (v2 >> 6); int c = v2 & 63;
                base = nb + (size_t)h * WP * CIN + c;
            } else {
                int v3 = v - 24832; int h = 1 + (v3 >> 6); int c = v3 & 63;
                base = nb + ((size_t)h * WP + 129) * CIN + c;
            }
            short8 z = {0, 0, 0, 0, 0, 0, 0, 0};
            *(short8*)&xp[base] = z;
        }
    } else {
        int gid = (bid - PRE_T - PRE_H) * 256 + t;
        if (gid < WAM) {
            int idx = gid;
            int jj = idx & 7;
            int lane = (idx >> 3) & 63;
            int kk = (idx >> 9) % NKK;
            int mt = (idx >> 9) / NKK;
            int o = mt * 16 + (lane & 15);
            int rp = kk * 32 + (lane >> 4) * 8 + jj;
            int k = rp >> 6, c = rp & 63;
            float w = weight[((size_t)o * CIN + c) * 9 + k];
            unsigned short h = f2bf(w);
            mhi[idx] = (short)h;
            mlo[idx] = (short)f2bf(w - bf2f(h));
        } else {
            int idx = gid - WAM;
            int jj = idx & 7;
            int lane = (idx >> 3) & 63;
            int kk = (idx >> 9) % NKK;
            int mt = (idx >> 9) / NKK;
            int j = mt * 16 + (lane & 15);
            int rp = kk * 32 + (lane >> 4) * 8 + jj;
            int k = rp >> 6, c = rp & 63;
            float w = 0.f;
            if (j < 18)      w = w_off[((size_t)j * CIN + c) * 9 + k];
            else if (j < 27) w = w_mask[((size_t)(j - 18) * CIN + c) * 9 + k];
            unsigned short h = f2bf(w);
            ohi[idx] = (short)h;
            olo[idx] = (short)f2bf(w - bf2f(h));
        }
    }
}

// ---------------- fused kernel ----------------
// grid (WD/TP, HD, NB), block 256. launch_bounds(256,6): 6 waves/EU -> 6 blocks/CU,
// VGPR cap ~85 so stage-4 gathers get ILP (R7's 40-VGPR build was latency-bound).
__global__ __launch_bounds__(256, 6) void fused_kernel(
    const unsigned short* __restrict__ xp,
    const short* __restrict__ waM_hi, const short* __restrict__ waM_lo,
    const short* __restrict__ waO_hi, const short* __restrict__ waO_lo,
    const float* __restrict__ b_off, const float* __restrict__ b_mask,
    const float* __restrict__ bias,
    float* __restrict__ out)
{
    __shared__ __align__(16) short val_hi[72 * 128];     // 18432 B
    __shared__ float conv_h[2][27 * 17];                 // split-K partials
    __shared__ float4 p_w4[K2 * TP];
    __shared__ unsigned int p_pk[K2 * TP];               // packed y0c+1,y1c+1,x0c+1,x1c+1

    int t = threadIdx.x;
    int wv = t >> 6;
    int lane = t & 63;
    int wo0 = blockIdx.x * TP;
    int ho  = blockIdx.y;
    int n   = blockIdx.z;
    const unsigned short* xpn = xp + (size_t)n * WP * WP * CIN;
    int p16 = lane & 15, quad = lane >> 4;

    // ---- stage 1: patch -> B-frag layout; pure 16B copies ----
    #pragma unroll
    for (int i = 0; i < 5; i++) {
        int u = t + 256 * i;
        if (u < K2 * TP * 8) {
            int tap = u >> 7;
            int p = (u >> 3) & 15;
            int g = u & 7;
            int ti = tap / 3, tj = tap - ti * 3;
            const short8 v = *(const short8*)&xpn[((size_t)(ho + ti) * WP + (wo0 + p + tj)) * CIN + g * 8];
            int c2 = tap * 8 + g;
            *(short8*)&val_hi[c2 * 128 + ((p + c2) & 15) * 8] = v;
        }
    }
    __syncthreads();

    // ---- stage 2: offset/mask conv GEMM, split-K over all 4 waves ----
    // wave wv: jtile = wv&1 (j in [16*jt,16*jt+16)), khalf = wv>>1 (kk in [9*kh, 9*kh+9))
    {
        int jt = wv & 1, kh = wv >> 1;
        f32x4 acc_h = {0.f, 0.f, 0.f, 0.f};
        f32x4 acc_l = {0.f, 0.f, 0.f, 0.f};
        #pragma unroll
        for (int q = 0; q < 9; q++) {
            int kk = kh * 9 + q;
            int abase = ((jt * NKK + kk) * 64 + lane) * 8;
            short8 ah = *(const short8*)&waO_hi[abase];
            short8 al = *(const short8*)&waO_lo[abase];
            int c2 = kk * 4 + quad;
            short8 b = *(const short8*)&val_hi[c2 * 128 + ((p16 + c2) & 15) * 8];
            acc_h = __builtin_amdgcn_mfma_f32_16x16x32_bf16(ah, b, acc_h, 0, 0, 0);
            acc_l = __builtin_amdgcn_mfma_f32_16x16x32_bf16(al, b, acc_l, 0, 0, 0);
        }
        #pragma unroll
        for (int i = 0; i < 4; i++) {
            int j = jt * 16 + quad * 4 + i;
            if (j < 27) conv_h[kh][j * 17 + p16] = acc_h[i] + acc_l[i];
        }
    }
    __syncthreads();

    // ---- stage 3: combine partials, sigmoid-modulate, bilinear params ----
    if (t < K2 * TP) {
        int k = t >> 4, p = t & 15;
        int r0 = (2 * k) * 17 + p;
        int r1 = (2 * k + 1) * 17 + p;
        int rm0 = (18 + (2 * k) % 9) * 17 + p;
        int rm1 = (18 + (2 * k + 1) % 9) * 17 + p;
        float oy_raw = conv_h[0][r0] + conv_h[1][r0] + b_off[2 * k];
        float ox_raw = conv_h[0][r1] + conv_h[1][r1] + b_off[2 * k + 1];
        float sm0 = conv_h[0][rm0] + conv_h[1][rm0] + b_mask[(2 * k) % 9];
        float sm1 = conv_h[0][rm1] + conv_h[1][rm1] + b_mask[(2 * k + 1) % 9];
        float my = 1.f / (1.f + expf(-sm0));
        float mx = 1.f / (1.f + expf(-sm1));
        float oy = oy_raw * my;
        float ox = ox_raw * mx;
        int ki = k / 3, kj = k - ki * 3;
        int wo = wo0 + p;
        float py = (float)(ho - 1 + ki) + oy;
        float px = (float)(wo - 1 + kj) + ox;
        float y0f = floorf(py), x0f = floorf(px);
        float wy = py - y0f, wx = px - x0f;
        int y0 = (int)y0f, x0 = (int)x0f;
        float wy0 = 1.f - wy, wx0 = 1.f - wx;
        int y0c = min(max(y0, 0), HD - 1);
        int y1c = min(max(y0 + 1, 0), HD - 1);
        int x0c = min(max(x0, 0), WD - 1);
        int x1c = min(max(x0 + 1, 0), WD - 1);
        bool vy0 = (y0 >= 0) && (y0 < HD);
        bool vy1 = (y0 + 1 >= 0) && (y0 + 1 < HD);
        bool vx0 = (x0 >= 0) && (x0 < WD);
        bool vx1 = (x0 + 1 >= 0) && (x0 + 1 < WD);
        float4 w4;
        w4.x = (vy0 && vx0) ? wy0 * wx0 : 0.f;
        w4.y = (vy0 && vx1) ? wy0 * wx  : 0.f;
        w4.z = (vy1 && vx0) ? wy  * wx0 : 0.f;
        w4.w = (vy1 && vx1) ? wy  * wx  : 0.f;
        p_w4[t] = w4;
        p_pk[t] = (unsigned int)(y0c + 1) | ((unsigned int)(y1c + 1) << 8)
                | ((unsigned int)(x0c + 1) << 16) | ((unsigned int)(x1c + 1) << 24);
    }
    __syncthreads();

    // ---- stage 4: bilinear gather, 4 channels/lane -> ds_write_b64 ----
    {
        int sub = lane >> 4;
        int c0 = (lane & 15) * 4;
        #pragma unroll
        for (int i = 0; i < 9; i++) {
            int task = i * 16 + wv * 4 + sub;
            int k = task >> 4, p = task & 15;
            float4 w4 = p_w4[task];
            unsigned int pk = p_pk[task];
            int y0b = (int)(pk & 255) * (WP * CIN);
            int y1b = (int)((pk >> 8) & 255) * (WP * CIN);
            int x0b = (int)((pk >> 16) & 255) * CIN + c0;
            int x1b = (int)(pk >> 24) * CIN + c0;
            uint2 qa = *(const uint2*)&xpn[y0b + x0b];
            uint2 qb = *(const uint2*)&xpn[y0b + x1b];
            uint2 qc = *(const uint2*)&xpn[y1b + x0b];
            uint2 qd = *(const uint2*)&xpn[y1b + x1b];
            float g0 = w4.x * __uint_as_float(qa.x << 16)
                     + w4.y * __uint_as_float(qb.x << 16)
                     + w4.z * __uint_as_float(qc.x << 16)
                     + w4.w * __uint_as_float(qd.x << 16);
            float g1 = w4.x * __uint_as_float(qa.x & 0xffff0000u)
                     + w4.y * __uint_as_float(qb.x & 0xffff0000u)
                     + w4.z * __uint_as_float(qc.x & 0xffff0000u)
                     + w4.w * __uint_as_float(qd.x & 0xffff0000u);
            float g2 = w4.x * __uint_as_float(qa.y << 16)
                     + w4.y * __uint_as_float(qb.y << 16)
                     + w4.z * __uint_as_float(qc.y << 16)
                     + w4.w * __uint_as_float(qd.y << 16);
            float g3 = w4.x * __uint_as_float(qa.y & 0xffff0000u)
                     + w4.y * __uint_as_float(qb.y & 0xffff0000u)
                     + w4.z * __uint_as_float(qc.y & 0xffff0000u)
                     + w4.w * __uint_as_float(qd.y & 0xffff0000u);
            uint2 r;
            r.x = pack_bf16(g0, g1);
            r.y = pack_bf16(g2, g3);
            int c2 = k * 8 + (c0 >> 3);
            int jj = c0 & 7;
            *(uint2*)&val_hi[c2 * 128 + ((p + c2) & 15) * 8 + jj] = r;
        }
    }
    __syncthreads();

    // ---- stage 5: main GEMM C[64 o][16 p], dual hi/lo chains, full unroll ----
    f32x4 acc_h = {0.f, 0.f, 0.f, 0.f};
    f32x4 acc_l = {0.f, 0.f, 0.f, 0.f};
    #pragma unroll
    for (int kk = 0; kk < NKK; kk++) {
        int abase = ((wv * NKK + kk) * 64 + lane) * 8;
        short8 ah = *(const short8*)&waM_hi[abase];
        short8 al = *(const short8*)&waM_lo[abase];
        int c2 = kk * 4 + quad;
        short8 b = *(const short8*)&val_hi[c2 * 128 + ((p16 + c2) & 15) * 8];
        acc_h = __builtin_amdgcn_mfma_f32_16x16x32_bf16(ah, b, acc_h, 0, 0, 0);
        acc_l = __builtin_amdgcn_mfma_f32_16x16x32_bf16(al, b, acc_l, 0, 0, 0);
    }

    // ---- epilogue: direct stores (same 64B-segment pattern as staged version) ----
    size_t obase = ((size_t)n * COUT) * HW + (size_t)ho * WD + wo0;
    #pragma unroll
    for (int i = 0; i < 4; i++) {
        int o = wv * 16 + quad * 4 + i;
        out[obase + (size_t)o * HW + p16] = acc_h[i] + acc_l[i] + bias[o];
    }
}

// ================= fallback path (R1-proven, fp32 NCHW) =================
__global__ void transpose_w_kernel(const float* __restrict__ w, float* __restrict__ wt) {
    int i = blockIdx.x * 256 + threadIdx.x;
    int o = i / CK;
    int ck = i - o * CK;
    wt[ck * COUT + o] = w[i];
}

__global__ __launch_bounds__(256) void offmask_kernel(
    const float* __restrict__ x,
    const float* __restrict__ w_off, const float* __restrict__ b_off,
    const float* __restrict__ w_mask, const float* __restrict__ b_mask,
    float* __restrict__ offy, float* __restrict__ offx)
{
    __shared__ float ws[CK][27];
    int t = threadIdx.x;
    for (int i = t; i < CK * 27; i += 256) {
        int j = i % 27;
        int citap = i / 27;
        int ci = citap / 9;
        int tap = citap - ci * 9;
        float v;
        if (j < 18) v = w_off[(j * CIN + ci) * 9 + tap];
        else        v = w_mask[((j - 18) * CIN + ci) * 9 + tap];
        ws[citap][j] = v;
    }
    __syncthreads();

    int pix = blockIdx.x * 256 + t;
    int n  = pix >> 14;
    int ho = (pix >> 7) & 127;
    int wo = pix & 127;

    float acc[27];
    #pragma unroll
    for (int j = 0; j < 18; j++) acc[j] = b_off[j];
    #pragma unroll
    for (int j = 0; j < 9; j++)  acc[18 + j] = b_mask[j];

    int offs[9];
    bool oks[9];
    #pragma unroll
    for (int dy = 0; dy < 3; dy++) {
        int y = ho - 1 + dy;
        #pragma unroll
        for (int dx = 0; dx < 3; dx++) {
            int xx = wo - 1 + dx;
            bool ok = (y >= 0) && (y < HD) && (xx >= 0) && (xx < WD);
            oks[dy * 3 + dx] = ok;
            offs[dy * 3 + dx] = (ok ? y : 0) * WD + (ok ? xx : 0);
        }
    }
    const float* xn = x + (size_t)n * CIN * HW;
    for (int ci = 0; ci < CIN; ci++) {
        const float* xc = xn + (size_t)ci * HW;
        float v[9];
        #pragma unroll
        for (int tap = 0; tap < 9; tap++)
            v[tap] = oks[tap] ? xc[offs[tap]] : 0.f;
        #pragma unroll
        for (int tap = 0; tap < 9; tap++) {
            const float* wrow = ws[ci * 9 + tap];
            float vv = v[tap];
            #pragma unroll
            for (int j = 0; j < 27; j++) acc[j] += wrow[j] * vv;
        }
    }
    float m[9];
    #pragma unroll
    for (int j = 0; j < 9; j++) m[j] = 1.f / (1.f + expf(-acc[18 + j]));
    #pragma unroll
    for (int k = 0; k < 9; k++) {
        int cy = 2 * k, cx = 2 * k + 1;
        float my = m[cy < 9 ? cy : cy - 9];
        float mx = m[cx < 9 ? cx : cx - 9];
        size_t o = (((size_t)n * K2 + k) * HD + ho) * WD + wo;
        offy[o] = acc[cy] * my;
        offx[o] = acc[cx] * mx;
    }
}

__global__ __launch_bounds__(256) void deform_kernel(
    const float* __restrict__ x,
    const float* __restrict__ offy, const float* __restrict__ offx,
    const float* __restrict__ wt,
    const float* __restrict__ bias,
    float* __restrict__ out)
{
    __shared__ __align__(16) float val_s[CK * TP];
    __shared__ float4 p_w4[K2 * TP];
    __shared__ int4   p_idx4[K2 * TP];

    int t = threadIdx.x;
    int wo0 = blockIdx.x * TP;
    int ho  = blockIdx.y;
    int n   = blockIdx.z;

    if (t < K2 * TP) {
        int k = t >> 4, p = t & 15;
        int wo = wo0 + p;
        size_t oi = (((size_t)n * K2 + k) * HD + ho) * WD + wo;
        float oy = offy[oi], ox = offx[oi];
        int ki = k / 3, kj = k - ki * 3;
        float py = (float)(ho - 1 + ki) + oy;
        float px = (float)(wo - 1 + kj) + ox;
        float y0f = floorf(py), x0f = floorf(px);
        float wy = py - y0f, wx = px - x0f;
        int y0 = (int)y0f, x0 = (int)x0f;
        float wy0 = 1.f - wy, wx0 = 1.f - wx;
        int y0c = min(max(y0, 0), HD - 1);
        int y1c = min(max(y0 + 1, 0), HD - 1);
        int x0c = min(max(x0, 0), WD - 1);
        int x1c = min(max(x0 + 1, 0), WD - 1);
        bool vy0 = (y0 >= 0) && (y0 < HD);
        bool vy1 = (y0 + 1 >= 0) && (y0 + 1 < HD);
        bool vx0 = (x0 >= 0) && (x0 < WD);
        bool vx1 = (x0 + 1 >= 0) && (x0 + 1 < WD);
        float4 w4;
        w4.x = (vy0 && vx0) ? wy0 * wx0 : 0.f;
        w4.y = (vy0 && vx1) ? wy0 * wx  : 0.f;
        w4.z = (vy1 && vx0) ? wy  * wx0 : 0.f;
        w4.w = (vy1 && vx1) ? wy  * wx  : 0.f;
        int4 i4;
        i4.x = y0c * WD + x0c;
        i4.y = y0c * WD + x1c;
        i4.z = y1c * WD + x0c;
        i4.w = y1c * WD + x1c;
        p_w4[t] = w4;
        p_idx4[t] = i4;
    }
    __syncthreads();

    const float* xn = x + (size_t)n * CIN * HW;
    for (int e = t; e < CK * TP; e += 256) {
        int row = e >> 4, p = e & 15;
        int cc = row / 9, k = row - cc * 9;
        int task = (k << 4) | p;
        float4 w4 = p_w4[task];
        int4  i4 = p_idx4[task];
        const float* xc = xn + (size_t)cc * HW;
        val_s[e] = w4.x * xc[i4.x] + w4.y * xc[i4.y]
                 + w4.z * xc[i4.z] + w4.w * xc[i4.w];
    }
    __syncthreads();

    int o = t & 63, q = t >> 6;
    float4 acc = {0.f, 0.f, 0.f, 0.f};
    const float4* v4 = (const float4*)val_s;
    const float* wp = wt + o;
    #pragma unroll 4
    for (int r = 0; r < CK; r++) {
        float w = wp[r * COUT];
        float4 vv = v4[r * 4 + q];
        acc.x += w * vv.x; acc.y += w * vv.y;
        acc.z += w * vv.z; acc.w += w * vv.w;
    }
    float b = bias[o];
    acc.x += b; acc.y += b; acc.z += b; acc.w += b;
    __syncthreads();
    float4* o4 = (float4*)val_s;
    o4[o * 4 + q] = acc;
    __syncthreads();
    size_t obase = ((size_t)n * COUT) * HW + (size_t)ho * WD + wo0;
    #pragma unroll
    for (int i = 0; i < 4; i++) {
        int l = t + 256 * i;
        int oo = l >> 4, p = l & 15;
        out[obase + (size_t)oo * HW + p] = val_s[l];
    }
}

extern "C" void kernel_launch(void* const* d_in, const int* in_sizes, int n_in,
                              void* d_out, int out_size, void* d_ws, size_t ws_size,
                              hipStream_t stream) {
    const float* x      = (const float*)d_in[0];
    const float* w_off  = (const float*)d_in[1];
    const float* b_off  = (const float*)d_in[2];
    const float* w_mask = (const float*)d_in[3];
    const float* b_mask = (const float*)d_in[4];
    const float* weight = (const float*)d_in[5];
    const float* bias   = (const float*)d_in[6];
    float* out = (float*)d_out;

    short* base = (short*)d_ws;
    short* waM_hi = base;
    short* waM_lo = waM_hi + WAM;
    short* waO_hi = waM_lo + WAM;
    short* waO_lo = waO_hi + WAO;
    unsigned short* xp = (unsigned short*)(waO_lo + WAO);
    size_t need = ((size_t)2 * WAM + 2 * WAO + XTP) * sizeof(short);

    if (ws_size >= need) {
        pre_kernel<<<PRE_T + PRE_H + PRE_P, 256, 0, stream>>>(
            x, weight, w_off, w_mask, xp, waM_hi, waM_lo, waO_hi, waO_lo);
        fused_kernel<<<dim3(WD / TP, HD, NB), 256, 0, stream>>>(
            xp, waM_hi, waM_lo, waO_hi, waO_lo, b_off, b_mask, bias, out);
    } else {
        float* offy = (float*)d_ws;
        float* offx = offy + OFFSZ;
        float* wt   = offx + OFFSZ;
        transpose_w_kernel<<<144, 256, 0, stream>>>(weight, wt);
        offmask_kernel<<<256, 256, 0, stream>>>(x, w_off, b_off, w_mask, b_mask, offy, offx);
        deform_kernel<<<dim3(WD / TP, HD, NB), 256, 0, stream>>>(x, offy, offx, wt, bias, out);
    }
}

// Round 9
// 124.846 us; speedup vs baseline: 2.9277x; 1.0307x over previous
//
#include <hip/hip_runtime.h>
#include <math.h>

#define HD 128
#define WD 128
#define WP 130              // padded width/height (1-halo)
#define CIN 64
#define COUT 64
#define NB 4
#define K2 9
#define HW (HD*WD)          // 16384
#define CK 576              // CIN*K2, K of both GEMMs (k-major permuted: r' = k*64+c)
#define TP 32               // pixels per block (fused kernel)
#define TPF 16              // pixels per block (fallback kernel)
#define NKK 18              // K-steps of 32

#define WAM   (4 * NKK * 64 * 8)             // 36864 shorts per main A-frag buffer
#define WAO   (2 * NKK * 64 * 8)             // 18432 shorts per offset A-frag buffer
#define XTP   ((size_t)NB * WP * WP * CIN)   // 4326400 shorts (padded NHWC bf16 x)
#define OFFSZ ((size_t)NB * K2 * HW)         // fallback
#define WTSZ  ((size_t)CK * COUT)            // fallback

// pre_kernel block partition
#define PRE_T 1024                            // transpose blocks
#define PRE_H 65                              // halo-zero blocks
#define PRE_P ((WAM + WAO) / 256)             // 216 prep blocks
#define HALO_PER_N 33024                      // halo shorts per image
#define HALO_W8 16512                         // total 8-short zero units

typedef __attribute__((ext_vector_type(8))) short short8;
typedef __attribute__((ext_vector_type(4))) float f32x4;

__device__ inline unsigned short f2bf(float v) {
    unsigned int u = __float_as_uint(v);
    unsigned int r = u + 0x7fffu + ((u >> 16) & 1u);
    return (unsigned short)(r >> 16);
}
__device__ inline float bf2f(unsigned short b) {
    return __uint_as_float(((unsigned int)b) << 16);
}
__device__ inline unsigned int pack_bf16(float a, float b) {
#if __has_builtin(__builtin_amdgcn_cvt_pk_bf16_f32)
    auto r = __builtin_amdgcn_cvt_pk_bf16_f32(a, b);
    unsigned int u; __builtin_memcpy(&u, &r, 4); return u;
#else
    return ((unsigned int)f2bf(b) << 16) | (unsigned int)f2bf(a);
#endif
}
// unpack dword of 2 bf16 -> float2 (written as float2 math so compiler can emit v_pk_fma_f32)
__device__ inline float2 up2(unsigned int u) {
    float2 r;
    r.x = __uint_as_float(u << 16);
    r.y = __uint_as_float(u & 0xffff0000u);
    return r;
}

// ---------------- merged pre-kernel: transpose | halo zero | weight prep ----------------
__global__ __launch_bounds__(256) void pre_kernel(
    const float* __restrict__ x,
    const float* __restrict__ weight,
    const float* __restrict__ w_off,
    const float* __restrict__ w_mask,
    unsigned short* __restrict__ xp,
    short* __restrict__ mhi, short* __restrict__ mlo,
    short* __restrict__ ohi, short* __restrict__ olo)
{
    __shared__ float tile[64][66];   // [w][c], pad 66
    int bid = blockIdx.x;
    int t = threadIdx.x;

    if (bid < PRE_T) {
        int half = bid & 1;
        int h = (bid >> 1) & 127;
        int n = bid >> 8;
        int w0 = half * 64;
        int g = t >> 6, wl = t & 63;
        const float* xb = x + ((size_t)n * CIN) * HW + h * WD + w0;
        #pragma unroll
        for (int i = 0; i < 16; i++) {
            int cc = i * 4 + g;
            tile[wl][cc] = xb[(size_t)cc * HW + wl];
        }
        __syncthreads();
        size_t rowbase = (((size_t)n * WP + (h + 1)) * WP + (w0 + 1)) * CIN;
        #pragma unroll
        for (int i = 0; i < 8; i++) {
            int u = i * 256 + t;
            int ww = u >> 5;
            int cp = (u & 31) * 2;
            float2 v = *(const float2*)&tile[ww][cp];
            *(unsigned int*)&xp[rowbase + (size_t)ww * CIN + cp] = pack_bf16(v.x, v.y);
        }
    } else if (bid < PRE_T + PRE_H) {
        int widx = (bid - PRE_T) * 256 + t;
        if (widx < HALO_W8) {
            int s = widx * 8;
            int n = s / HALO_PER_N;
            int v = s - n * HALO_PER_N;
            size_t nb = (size_t)n * WP * WP * CIN;
            size_t base;
            if (v < 8320) {
                base = nb + v;
            } else if (v < 16640) {
                base = nb + (size_t)129 * WP * CIN + (v - 8320);
            } else if (v < 24832) {
                int v2 = v - 16640; int h = 1 + (v2 >> 6); int c = v2 & 63;
                base = nb + (size_t)h * WP * CIN + c;
            } else {
                int v3 = v - 24832; int h = 1 + (v3 >> 6); int c = v3 & 63;
                base = nb + ((size_t)h * WP + 129) * CIN + c;
            }
            short8 z = {0, 0, 0, 0, 0, 0, 0, 0};
            *(short8*)&xp[base] = z;
        }
    } else {
        int gid = (bid - PRE_T - PRE_H) * 256 + t;
        if (gid < WAM) {
            int idx = gid;
            int jj = idx & 7;
            int lane = (idx >> 3) & 63;
            int kk = (idx >> 9) % NKK;
            int mt = (idx >> 9) / NKK;
            int o = mt * 16 + (lane & 15);
            int rp = kk * 32 + (lane >> 4) * 8 + jj;
            int k = rp >> 6, c = rp & 63;
            float w = weight[((size_t)o * CIN + c) * 9 + k];
            unsigned short h = f2bf(w);
            mhi[idx] = (short)h;
            mlo[idx] = (short)f2bf(w - bf2f(h));
        } else {
            int idx = gid - WAM;
            int jj = idx & 7;
            int lane = (idx >> 3) & 63;
            int kk = (idx >> 9) % NKK;
            int mt = (idx >> 9) / NKK;
            int j = mt * 16 + (lane & 15);
            int rp = kk * 32 + (lane >> 4) * 8 + jj;
            int k = rp >> 6, c = rp & 63;
            float w = 0.f;
            if (j < 18)      w = w_off[((size_t)j * CIN + c) * 9 + k];
            else if (j < 27) w = w_mask[((size_t)(j - 18) * CIN + c) * 9 + k];
            unsigned short h = f2bf(w);
            ohi[idx] = (short)h;
            olo[idx] = (short)f2bf(w - bf2f(h));
        }
    }
}

// ---------------- fused kernel, TP=32 ----------------
// grid (WD/TP=4, HD, NB), block 256, 3 blocks/CU (49.5 KB LDS).
// A-fragments loaded once per kk and reused across both p-tiles (halves A-frag L2 traffic).
__global__ __launch_bounds__(256, 3) void fused_kernel(
    const unsigned short* __restrict__ xp,
    const short* __restrict__ waM_hi, const short* __restrict__ waM_lo,
    const short* __restrict__ waO_hi, const short* __restrict__ waO_lo,
    const float* __restrict__ b_off, const float* __restrict__ b_mask,
    const float* __restrict__ bias,
    float* __restrict__ out)
{
    // B operand: 72 chunks x (32 p-slots x 8 jj) bf16, slot = (p + c2) & 31
    __shared__ __align__(16) short val_hi[72 * 256];     // 36864 B
    __shared__ float conv_s[27 * 32];                    // 3456 B (bias included)
    __shared__ float4 p_w4[K2 * TP];                     // 4608 B
    __shared__ int4   p_idx4[K2 * TP];                   // 4608 B (element offsets, *CIN applied)

    int t = threadIdx.x;
    int wv = t >> 6;
    int lane = t & 63;
    int wo0 = blockIdx.x * TP;
    int ho  = blockIdx.y;
    int n   = blockIdx.z;
    const unsigned short* xpn = xp + (size_t)n * WP * WP * CIN;
    int p16 = lane & 15, quad = lane >> 4;

    // ---- stage 1: patch -> B-frag layout; 2304 16B copies (9 exact iters) ----
    #pragma unroll
    for (int i = 0; i < 9; i++) {
        int u = t + 256 * i;
        int tap = u >> 8;
        int p = (u >> 3) & 31;
        int g = u & 7;
        int ti = tap / 3, tj = tap - ti * 3;
        const short8 v = *(const short8*)&xpn[((size_t)(ho + ti) * WP + (wo0 + p + tj)) * CIN + g * 8];
        int c2 = tap * 8 + g;
        *(short8*)&val_hi[c2 * 256 + ((p + c2) & 31) * 8] = v;
    }
    __syncthreads();

    // ---- stage 2: offset/mask conv GEMM; wave = (jt, pt); A reused, dual hi/lo chains ----
    {
        int jt = wv >> 1, pt = wv & 1;
        f32x4 acc_h = {0.f, 0.f, 0.f, 0.f};
        f32x4 acc_l = {0.f, 0.f, 0.f, 0.f};
        #pragma unroll
        for (int kk = 0; kk < NKK; kk++) {
            int abase = ((jt * NKK + kk) * 64 + lane) * 8;
            short8 ah = *(const short8*)&waO_hi[abase];
            short8 al = *(const short8*)&waO_lo[abase];
            int c2 = kk * 4 + quad;
            short8 b = *(const short8*)&val_hi[c2 * 256 + ((pt * 16 + p16 + c2) & 31) * 8];
            acc_h = __builtin_amdgcn_mfma_f32_16x16x32_bf16(ah, b, acc_h, 0, 0, 0);
            acc_l = __builtin_amdgcn_mfma_f32_16x16x32_bf16(al, b, acc_l, 0, 0, 0);
        }
        #pragma unroll
        for (int i = 0; i < 4; i++) {
            int j = jt * 16 + quad * 4 + i;
            if (j < 27) {
                float bv = (j < 18) ? b_off[j] : b_mask[j - 18];
                conv_s[j * 32 + pt * 16 + p16] = acc_h[i] + acc_l[i] + bv;
            }
        }
    }
    __syncthreads();

    // ---- stage 3: sigmoid-modulated offsets -> bilinear params (288 tasks) ----
    #pragma unroll
    for (int pass = 0; pass < 2; pass++) {
        int u = t + pass * 256;
        if (u < K2 * TP) {
            int k = u >> 5, p = u & 31;
            float oy_raw = conv_s[(2 * k) * 32 + p];
            float ox_raw = conv_s[(2 * k + 1) * 32 + p];
            float my = 1.f / (1.f + expf(-conv_s[(18 + (2 * k) % 9) * 32 + p]));
            float mx = 1.f / (1.f + expf(-conv_s[(18 + (2 * k + 1) % 9) * 32 + p]));
            float oy = oy_raw * my;
            float ox = ox_raw * mx;
            int ki = k / 3, kj = k - ki * 3;
            int wo = wo0 + p;
            float py = (float)(ho - 1 + ki) + oy;
            float px = (float)(wo - 1 + kj) + ox;
            float y0f = floorf(py), x0f = floorf(px);
            float wy = py - y0f, wx = px - x0f;
            int y0 = (int)y0f, x0 = (int)x0f;
            float wy0 = 1.f - wy, wx0 = 1.f - wx;
            int y0c = min(max(y0, 0), HD - 1);
            int y1c = min(max(y0 + 1, 0), HD - 1);
            int x0c = min(max(x0, 0), WD - 1);
            int x1c = min(max(x0 + 1, 0), WD - 1);
            bool vy0 = (y0 >= 0) && (y0 < HD);
            bool vy1 = (y0 + 1 >= 0) && (y0 + 1 < HD);
            bool vx0 = (x0 >= 0) && (x0 < WD);
            bool vx1 = (x0 + 1 >= 0) && (x0 + 1 < WD);
            float4 w4;
            w4.x = (vy0 && vx0) ? wy0 * wx0 : 0.f;
            w4.y = (vy0 && vx1) ? wy0 * wx  : 0.f;
            w4.z = (vy1 && vx0) ? wy  * wx0 : 0.f;
            w4.w = (vy1 && vx1) ? wy  * wx  : 0.f;
            int4 i4;
            i4.x = ((y0c + 1) * WP + (x0c + 1)) * CIN;
            i4.y = ((y0c + 1) * WP + (x1c + 1)) * CIN;
            i4.z = ((y1c + 1) * WP + (x0c + 1)) * CIN;
            i4.w = ((y1c + 1) * WP + (x1c + 1)) * CIN;
            p_w4[u] = w4;
            p_idx4[u] = i4;
        }
    }
    __syncthreads();

    // ---- stage 4: bilinear gather, 4 channels/lane, float2 combine (18 exact iters) ----
    #pragma unroll
    for (int i = 0; i < 18; i++) {
        int u = t + 256 * i;
        int task = u >> 4;
        int c0 = (u & 15) * 4;
        int k = task >> 5, p = task & 31;
        float4 w4 = p_w4[task];
        int4  i4 = p_idx4[task];
        uint2 qa = *(const uint2*)&xpn[i4.x + c0];
        uint2 qb = *(const uint2*)&xpn[i4.y + c0];
        uint2 qc = *(const uint2*)&xpn[i4.z + c0];
        uint2 qd = *(const uint2*)&xpn[i4.w + c0];
        float2 ga = up2(qa.x), gb = up2(qb.x), gc = up2(qc.x), gd = up2(qd.x);
        float2 g01;
        g01.x = w4.x * ga.x + w4.y * gb.x + w4.z * gc.x + w4.w * gd.x;
        g01.y = w4.x * ga.y + w4.y * gb.y + w4.z * gc.y + w4.w * gd.y;
        float2 ha = up2(qa.y), hb = up2(qb.y), hc = up2(qc.y), hd = up2(qd.y);
        float2 g23;
        g23.x = w4.x * ha.x + w4.y * hb.x + w4.z * hc.x + w4.w * hd.x;
        g23.y = w4.x * ha.y + w4.y * hb.y + w4.z * hc.y + w4.w * hd.y;
        uint2 r;
        r.x = pack_bf16(g01.x, g01.y);
        r.y = pack_bf16(g23.x, g23.y);
        int c2 = k * 8 + (c0 >> 3);
        int jj = c0 & 7;
        *(uint2*)&val_hi[c2 * 256 + ((p + c2) & 31) * 8 + jj] = r;
    }
    __syncthreads();

    // ---- stage 5: main GEMM C[64 o][32 p]; wave = o-tile; A reused across both p-tiles ----
    f32x4 a0 = {0.f, 0.f, 0.f, 0.f};
    f32x4 a1 = {0.f, 0.f, 0.f, 0.f};
    #pragma unroll
    for (int kk = 0; kk < NKK; kk++) {
        int abase = ((wv * NKK + kk) * 64 + lane) * 8;
        short8 ah = *(const short8*)&waM_hi[abase];
        short8 al = *(const short8*)&waM_lo[abase];
        int c2 = kk * 4 + quad;
        short8 b0 = *(const short8*)&val_hi[c2 * 256 + ((p16 + c2) & 31) * 8];
        short8 b1 = *(const short8*)&val_hi[c2 * 256 + ((16 + p16 + c2) & 31) * 8];
        a0 = __builtin_amdgcn_mfma_f32_16x16x32_bf16(ah, b0, a0, 0, 0, 0);
        a1 = __builtin_amdgcn_mfma_f32_16x16x32_bf16(ah, b1, a1, 0, 0, 0);
        a0 = __builtin_amdgcn_mfma_f32_16x16x32_bf16(al, b0, a0, 0, 0, 0);
        a1 = __builtin_amdgcn_mfma_f32_16x16x32_bf16(al, b1, a1, 0, 0, 0);
    }

    // ---- epilogue: direct stores ----
    size_t obase = ((size_t)n * COUT) * HW + (size_t)ho * WD + wo0;
    #pragma unroll
    for (int i = 0; i < 4; i++) {
        int o = wv * 16 + quad * 4 + i;
        float bv = bias[o];
        out[obase + (size_t)o * HW + p16] = a0[i] + bv;
        out[obase + (size_t)o * HW + 16 + p16] = a1[i] + bv;
    }
}

// ================= fallback path (R1-proven, fp32 NCHW, TPF=16) =================
__global__ void transpose_w_kernel(const float* __restrict__ w, float* __restrict__ wt) {
    int i = blockIdx.x * 256 + threadIdx.x;
    int o = i / CK;
    int ck = i - o * CK;
    wt[ck * COUT + o] = w[i];
}

__global__ __launch_bounds__(256) void offmask_kernel(
    const float* __restrict__ x,
    const float* __restrict__ w_off, const float* __restrict__ b_off,
    const float* __restrict__ w_mask, const float* __restrict__ b_mask,
    float* __restrict__ offy, float* __restrict__ offx)
{
    __shared__ float ws[CK][27];
    int t = threadIdx.x;
    for (int i = t; i < CK * 27; i += 256) {
        int j = i % 27;
        int citap = i / 27;
        int ci = citap / 9;
        int tap = citap - ci * 9;
        float v;
        if (j < 18) v = w_off[(j * CIN + ci) * 9 + tap];
        else        v = w_mask[((j - 18) * CIN + ci) * 9 + tap];
        ws[citap][j] = v;
    }
    __syncthreads();

    int pix = blockIdx.x * 256 + t;
    int n  = pix >> 14;
    int ho = (pix >> 7) & 127;
    int wo = pix & 127;

    float acc[27];
    #pragma unroll
    for (int j = 0; j < 18; j++) acc[j] = b_off[j];
    #pragma unroll
    for (int j = 0; j < 9; j++)  acc[18 + j] = b_mask[j];

    int offs[9];
    bool oks[9];
    #pragma unroll
    for (int dy = 0; dy < 3; dy++) {
        int y = ho - 1 + dy;
        #pragma unroll
        for (int dx = 0; dx < 3; dx++) {
            int xx = wo - 1 + dx;
            bool ok = (y >= 0) && (y < HD) && (xx >= 0) && (xx < WD);
            oks[dy * 3 + dx] = ok;
            offs[dy * 3 + dx] = (ok ? y : 0) * WD + (ok ? xx : 0);
        }
    }
    const float* xn = x + (size_t)n * CIN * HW;
    for (int ci = 0; ci < CIN; ci++) {
        const float* xc = xn + (size_t)ci * HW;
        float v[9];
        #pragma unroll
        for (int tap = 0; tap < 9; tap++)
            v[tap] = oks[tap] ? xc[offs[tap]] : 0.f;
        #pragma unroll
        for (int tap = 0; tap < 9; tap++) {
            const float* wrow = ws[ci * 9 + tap];
            float vv = v[tap];
            #pragma unroll
            for (int j = 0; j < 27; j++) acc[j] += wrow[j] * vv;
        }
    }
    float m[9];
    #pragma unroll
    for (int j = 0; j < 9; j++) m[j] = 1.f / (1.f + expf(-acc[18 + j]));
    #pragma unroll
    for (int k = 0; k < 9; k++) {
        int cy = 2 * k, cx = 2 * k + 1;
        float my = m[cy < 9 ? cy : cy - 9];
        float mx = m[cx < 9 ? cx : cx - 9];
        size_t o = (((size_t)n * K2 + k) * HD + ho) * WD + wo;
        offy[o] = acc[cy] * my;
        offx[o] = acc[cx] * mx;
    }
}

__global__ __launch_bounds__(256) void deform_kernel(
    const float* __restrict__ x,
    const float* __restrict__ offy, const float* __restrict__ offx,
    const float* __restrict__ wt,
    const float* __restrict__ bias,
    float* __restrict__ out)
{
    __shared__ __align__(16) float val_s[CK * TPF];
    __shared__ float4 p_w4[K2 * TPF];
    __shared__ int4   p_idx4[K2 * TPF];

    int t = threadIdx.x;
    int wo0 = blockIdx.x * TPF;
    int ho  = blockIdx.y;
    int n   = blockIdx.z;

    if (t < K2 * TPF) {
        int k = t >> 4, p = t & 15;
        int wo = wo0 + p;
        size_t oi = (((size_t)n * K2 + k) * HD + ho) * WD + wo;
        float oy = offy[oi], ox = offx[oi];
        int ki = k / 3, kj = k - ki * 3;
        float py = (float)(ho - 1 + ki) + oy;
        float px = (float)(wo - 1 + kj) + ox;
        float y0f = floorf(py), x0f = floorf(px);
        float wy = py - y0f, wx = px - x0f;
        int y0 = (int)y0f, x0 = (int)x0f;
        float wy0 = 1.f - wy, wx0 = 1.f - wx;
        int y0c = min(max(y0, 0), HD - 1);
        int y1c = min(max(y0 + 1, 0), HD - 1);
        int x0c = min(max(x0, 0), WD - 1);
        int x1c = min(max(x0 + 1, 0), WD - 1);
        bool vy0 = (y0 >= 0) && (y0 < HD);
        bool vy1 = (y0 + 1 >= 0) && (y0 + 1 < HD);
        bool vx0 = (x0 >= 0) && (x0 < WD);
        bool vx1 = (x0 + 1 >= 0) && (x0 + 1 < WD);
        float4 w4;
        w4.x = (vy0 && vx0) ? wy0 * wx0 : 0.f;
        w4.y = (vy0 && vx1) ? wy0 * wx  : 0.f;
        w4.z = (vy1 && vx0) ? wy  * wx0 : 0.f;
        w4.w = (vy1 && vx1) ? wy  * wx  : 0.f;
        int4 i4;
        i4.x = y0c * WD + x0c;
        i4.y = y0c * WD + x1c;
        i4.z = y1c * WD + x0c;
        i4.w = y1c * WD + x1c;
        p_w4[t] = w4;
        p_idx4[t] = i4;
    }
    __syncthreads();

    const float* xn = x + (size_t)n * CIN * HW;
    for (int e = t; e < CK * TPF; e += 256) {
        int row = e >> 4, p = e & 15;
        int cc = row / 9, k = row - cc * 9;
        int task = (k << 4) | p;
        float4 w4 = p_w4[task];
        int4  i4 = p_idx4[task];
        const float* xc = xn + (size_t)cc * HW;
        val_s[e] = w4.x * xc[i4.x] + w4.y * xc[i4.y]
                 + w4.z * xc[i4.z] + w4.w * xc[i4.w];
    }
    __syncthreads();

    int o = t & 63, q = t >> 6;
    float4 acc = {0.f, 0.f, 0.f, 0.f};
    const float4* v4 = (const float4*)val_s;
    const float* wp = wt + o;
    #pragma unroll 4
    for (int r = 0; r < CK; r++) {
        float w = wp[r * COUT];
        float4 vv = v4[r * 4 + q];
        acc.x += w * vv.x; acc.y += w * vv.y;
        acc.z += w * vv.z; acc.w += w * vv.w;
    }
    float b = bias[o];
    acc.x += b; acc.y += b; acc.z += b; acc.w += b;
    __syncthreads();
    float4* o4 = (float4*)val_s;
    o4[o * 4 + q] = acc;
    __syncthreads();
    size_t obase = ((size_t)n * COUT) * HW + (size_t)ho * WD + wo0;
    #pragma unroll
    for (int i = 0; i < 4; i++) {
        int l = t + 256 * i;
        int oo = l >> 4, p = l & 15;
        out[obase + (size_t)oo * HW + p] = val_s[l];
    }
}

extern "C" void kernel_launch(void* const* d_in, const int* in_sizes, int n_in,
                              void* d_out, int out_size, void* d_ws, size_t ws_size,
                              hipStream_t stream) {
    const float* x      = (const float*)d_in[0];
    const float* w_off  = (const float*)d_in[1];
    const float* b_off  = (const float*)d_in[2];
    const float* w_mask = (const float*)d_in[3];
    const float* b_mask = (const float*)d_in[4];
    const float* weight = (const float*)d_in[5];
    const float* bias   = (const float*)d_in[6];
    float* out = (float*)d_out;

    short* base = (short*)d_ws;
    short* waM_hi = base;
    short* waM_lo = waM_hi + WAM;
    short* waO_hi = waM_lo + WAM;
    short* waO_lo = waO_hi + WAO;
    unsigned short* xp = (unsigned short*)(waO_lo + WAO);
    size_t need = ((size_t)2 * WAM + 2 * WAO + XTP) * sizeof(short);

    if (ws_size >= need) {
        pre_kernel<<<PRE_T + PRE_H + PRE_P, 256, 0, stream>>>(
            x, weight, w_off, w_mask, xp, waM_hi, waM_lo, waO_hi, waO_lo);
        fused_kernel<<<dim3(WD / TP, HD, NB), 256, 0, stream>>>(
            xp, waM_hi, waM_lo, waO_hi, waO_lo, b_off, b_mask, bias, out);
    } else {
        float* offy = (float*)d_ws;
        float* offx = offy + OFFSZ;
        float* wt   = offx + OFFSZ;
        transpose_w_kernel<<<144, 256, 0, stream>>>(weight, wt);
        offmask_kernel<<<256, 256, 0, stream>>>(x, w_off, b_off, w_mask, b_mask, offy, offx);
        deform_kernel<<<dim3(WD / TPF, HD, NB), 256, 0, stream>>>(x, offy, offx, wt, bias, out);
    }
}

// Round 10
// 111.879 us; speedup vs baseline: 3.2670x; 1.1159x over previous
//
#include <hip/hip_runtime.h>
#include <math.h>

#define HD 128
#define WD 128
#define WP 130              // padded width/height (1-halo)
#define CIN 64
#define COUT 64
#define NB 4
#define K2 9
#define HW (HD*WD)          // 16384
#define CK 576              // CIN*K2, K of both GEMMs (k-major permuted: r' = k*64+c)
#define TP 32               // pixels per block (fused kernel)
#define TPF 16              // pixels per block (fallback kernel)
#define NKK 18              // K-steps of 32

#define WAM   (4 * NKK * 64 * 8)             // 36864 shorts main A-frag buffer (hi only)
#define WAO   (2 * NKK * 64 * 8)             // 18432 shorts offset A-frag buffer (hi only)
#define XTP   ((size_t)NB * WP * WP * CIN)   // 4326400 shorts (padded NHWC bf16 x)
#define OFFSZ ((size_t)NB * K2 * HW)         // fallback
#define WTSZ  ((size_t)CK * COUT)            // fallback

// pre_kernel block partition
#define PRE_T 1024                            // transpose blocks
#define PRE_H 65                              // halo-zero blocks
#define PRE_P ((WAM + WAO) / 256)             // 216 prep blocks
#define HALO_PER_N 33024                      // halo shorts per image
#define HALO_W8 16512                         // total 8-short zero units

typedef __attribute__((ext_vector_type(8))) short short8;
typedef __attribute__((ext_vector_type(4))) float f32x4;

__device__ inline unsigned short f2bf(float v) {
    unsigned int u = __float_as_uint(v);
    unsigned int r = u + 0x7fffu + ((u >> 16) & 1u);
    return (unsigned short)(r >> 16);
}
__device__ inline float bf2f(unsigned short b) {
    return __uint_as_float(((unsigned int)b) << 16);
}
__device__ inline unsigned int pack_bf16(float a, float b) {
#if __has_builtin(__builtin_amdgcn_cvt_pk_bf16_f32)
    auto r = __builtin_amdgcn_cvt_pk_bf16_f32(a, b);
    unsigned int u; __builtin_memcpy(&u, &r, 4); return u;
#else
    return ((unsigned int)f2bf(b) << 16) | (unsigned int)f2bf(a);
#endif
}
// unpack dword of 2 bf16 -> float2
__device__ inline float2 up2(unsigned int u) {
    float2 r;
    r.x = __uint_as_float(u << 16);
    r.y = __uint_as_float(u & 0xffff0000u);
    return r;
}

// ---------------- merged pre-kernel: transpose | halo zero | weight prep ----------------
__global__ __launch_bounds__(256) void pre_kernel(
    const float* __restrict__ x,
    const float* __restrict__ weight,
    const float* __restrict__ w_off,
    const float* __restrict__ w_mask,
    unsigned short* __restrict__ xp,
    short* __restrict__ mhi, short* __restrict__ ohi)
{
    __shared__ float tile[64][66];   // [w][c], pad 66
    int bid = blockIdx.x;
    int t = threadIdx.x;

    if (bid < PRE_T) {
        int half = bid & 1;
        int h = (bid >> 1) & 127;
        int n = bid >> 8;
        int w0 = half * 64;
        int g = t >> 6, wl = t & 63;
        const float* xb = x + ((size_t)n * CIN) * HW + h * WD + w0;
        #pragma unroll
        for (int i = 0; i < 16; i++) {
            int cc = i * 4 + g;
            tile[wl][cc] = xb[(size_t)cc * HW + wl];
        }
        __syncthreads();
        size_t rowbase = (((size_t)n * WP + (h + 1)) * WP + (w0 + 1)) * CIN;
        #pragma unroll
        for (int i = 0; i < 8; i++) {
            int u = i * 256 + t;
            int ww = u >> 5;
            int cp = (u & 31) * 2;
            float2 v = *(const float2*)&tile[ww][cp];
            *(unsigned int*)&xp[rowbase + (size_t)ww * CIN + cp] = pack_bf16(v.x, v.y);
        }
    } else if (bid < PRE_T + PRE_H) {
        int widx = (bid - PRE_T) * 256 + t;
        if (widx < HALO_W8) {
            int s = widx * 8;
            int n = s / HALO_PER_N;
            int v = s - n * HALO_PER_N;
            size_t nb = (size_t)n * WP * WP * CIN;
            size_t base;
            if (v < 8320) {
                base = nb + v;
            } else if (v < 16640) {
                base = nb + (size_t)129 * WP * CIN + (v - 8320);
            } else if (v < 24832) {
                int v2 = v - 16640; int h = 1 + (v2 >> 6); int c = v2 & 63;
                base = nb + (size_t)h * WP * CIN + c;
            } else {
                int v3 = v - 24832; int h = 1 + (v3 >> 6); int c = v3 & 63;
                base = nb + ((size_t)h * WP + 129) * CIN + c;
            }
            short8 z = {0, 0, 0, 0, 0, 0, 0, 0};
            *(short8*)&xp[base] = z;
        }
    } else {
        int gid = (bid - PRE_T - PRE_H) * 256 + t;
        if (gid < WAM) {
            int idx = gid;
            int jj = idx & 7;
            int lane = (idx >> 3) & 63;
            int kk = (idx >> 9) % NKK;
            int mt = (idx >> 9) / NKK;
            int o = mt * 16 + (lane & 15);
            int rp = kk * 32 + (lane >> 4) * 8 + jj;
            int k = rp >> 6, c = rp & 63;
            mhi[idx] = (short)f2bf(weight[((size_t)o * CIN + c) * 9 + k]);
        } else {
            int idx = gid - WAM;
            int jj = idx & 7;
            int lane = (idx >> 3) & 63;
            int kk = (idx >> 9) % NKK;
            int mt = (idx >> 9) / NKK;
            int j = mt * 16 + (lane & 15);
            int rp = kk * 32 + (lane >> 4) * 8 + jj;
            int k = rp >> 6, c = rp & 63;
            float w = 0.f;
            if (j < 18)      w = w_off[((size_t)j * CIN + c) * 9 + k];
            else if (j < 27) w = w_mask[((size_t)(j - 18) * CIN + c) * 9 + k];
            ohi[idx] = (short)f2bf(w);
        }
    }
}

// ---------------- fused kernel, TP=32, single-bf16 A ----------------
// grid (WD/TP=4, HD, NB), block 256, 3 blocks/CU (49.5 KB LDS).
__global__ __launch_bounds__(256, 3) void fused_kernel(
    const unsigned short* __restrict__ xp,
    const short* __restrict__ waM_hi,
    const short* __restrict__ waO_hi,
    const float* __restrict__ b_off, const float* __restrict__ b_mask,
    const float* __restrict__ bias,
    float* __restrict__ out)
{
    // B operand: 72 chunks x (32 p-slots x 8 jj) bf16, slot = (p + c2) & 31
    __shared__ __align__(16) short val_hi[72 * 256];     // 36864 B
    __shared__ float conv_s[27 * 32];                    // 3456 B (bias included)
    __shared__ float4 p_w4[K2 * TP];                     // 4608 B
    __shared__ int4   p_idx4[K2 * TP];                   // 4608 B (element offsets, *CIN applied)

    int t = threadIdx.x;
    int wv = t >> 6;
    int lane = t & 63;
    int wo0 = blockIdx.x * TP;
    int ho  = blockIdx.y;
    int n   = blockIdx.z;
    const unsigned short* xpn = xp + (size_t)n * WP * WP * CIN;
    int p16 = lane & 15, quad = lane >> 4;

    // ---- stage 1: patch -> B-frag layout; 2304 16B copies (9 exact iters) ----
    #pragma unroll
    for (int i = 0; i < 9; i++) {
        int u = t + 256 * i;
        int tap = u >> 8;
        int p = (u >> 3) & 31;
        int g = u & 7;
        int ti = tap / 3, tj = tap - ti * 3;
        const short8 v = *(const short8*)&xpn[((size_t)(ho + ti) * WP + (wo0 + p + tj)) * CIN + g * 8];
        int c2 = tap * 8 + g;
        *(short8*)&val_hi[c2 * 256 + ((p + c2) & 31) * 8] = v;
    }
    __syncthreads();

    // ---- stage 2: offset/mask conv GEMM; wave = (jt, pt); single-A chain ----
    {
        int jt = wv >> 1, pt = wv & 1;
        f32x4 acc = {0.f, 0.f, 0.f, 0.f};
        #pragma unroll
        for (int kk = 0; kk < NKK; kk++) {
            int abase = ((jt * NKK + kk) * 64 + lane) * 8;
            short8 ah = *(const short8*)&waO_hi[abase];
            int c2 = kk * 4 + quad;
            short8 b = *(const short8*)&val_hi[c2 * 256 + ((pt * 16 + p16 + c2) & 31) * 8];
            acc = __builtin_amdgcn_mfma_f32_16x16x32_bf16(ah, b, acc, 0, 0, 0);
        }
        #pragma unroll
        for (int i = 0; i < 4; i++) {
            int j = jt * 16 + quad * 4 + i;
            if (j < 27) {
                float bv = (j < 18) ? b_off[j] : b_mask[j - 18];
                conv_s[j * 32 + pt * 16 + p16] = acc[i] + bv;
            }
        }
    }
    __syncthreads();

    // ---- stage 3: sigmoid-modulated offsets -> bilinear params (288 tasks) ----
    #pragma unroll
    for (int pass = 0; pass < 2; pass++) {
        int u = t + pass * 256;
        if (u < K2 * TP) {
            int k = u >> 5, p = u & 31;
            float oy_raw = conv_s[(2 * k) * 32 + p];
            float ox_raw = conv_s[(2 * k + 1) * 32 + p];
            float my = 1.f / (1.f + expf(-conv_s[(18 + (2 * k) % 9) * 32 + p]));
            float mx = 1.f / (1.f + expf(-conv_s[(18 + (2 * k + 1) % 9) * 32 + p]));
            float oy = oy_raw * my;
            float ox = ox_raw * mx;
            int ki = k / 3, kj = k - ki * 3;
            int wo = wo0 + p;
            float py = (float)(ho - 1 + ki) + oy;
            float px = (float)(wo - 1 + kj) + ox;
            float y0f = floorf(py), x0f = floorf(px);
            float wy = py - y0f, wx = px - x0f;
            int y0 = (int)y0f, x0 = (int)x0f;
            float wy0 = 1.f - wy, wx0 = 1.f - wx;
            int y0c = min(max(y0, 0), HD - 1);
            int y1c = min(max(y0 + 1, 0), HD - 1);
            int x0c = min(max(x0, 0), WD - 1);
            int x1c = min(max(x0 + 1, 0), WD - 1);
            bool vy0 = (y0 >= 0) && (y0 < HD);
            bool vy1 = (y0 + 1 >= 0) && (y0 + 1 < HD);
            bool vx0 = (x0 >= 0) && (x0 < WD);
            bool vx1 = (x0 + 1 >= 0) && (x0 + 1 < WD);
            float4 w4;
            w4.x = (vy0 && vx0) ? wy0 * wx0 : 0.f;
            w4.y = (vy0 && vx1) ? wy0 * wx  : 0.f;
            w4.z = (vy1 && vx0) ? wy  * wx0 : 0.f;
            w4.w = (vy1 && vx1) ? wy  * wx  : 0.f;
            int4 i4;
            i4.x = ((y0c + 1) * WP + (x0c + 1)) * CIN;
            i4.y = ((y0c + 1) * WP + (x1c + 1)) * CIN;
            i4.z = ((y1c + 1) * WP + (x0c + 1)) * CIN;
            i4.w = ((y1c + 1) * WP + (x1c + 1)) * CIN;
            p_w4[u] = w4;
            p_idx4[u] = i4;
        }
    }
    __syncthreads();

    // ---- stage 4: bilinear gather, 8 channels/lane, dwordx4 loads + ds_write_b128 ----
    // unit u = task*8 + g ; 288 tasks x 8 groups = 2304 units, 9 exact iters
    #pragma unroll
    for (int i = 0; i < 9; i++) {
        int u = t + 256 * i;
        int task = u >> 3;
        int g = u & 7;
        int c0 = g * 8;
        int k = task >> 5, p = task & 31;
        float4 w4 = p_w4[task];
        int4  i4 = p_idx4[task];
        uint4 qa = *(const uint4*)&xpn[i4.x + c0];
        uint4 qb = *(const uint4*)&xpn[i4.y + c0];
        uint4 qc = *(const uint4*)&xpn[i4.z + c0];
        uint4 qd = *(const uint4*)&xpn[i4.w + c0];
        unsigned int qa_[4] = {qa.x, qa.y, qa.z, qa.w};
        unsigned int qb_[4] = {qb.x, qb.y, qb.z, qb.w};
        unsigned int qc_[4] = {qc.x, qc.y, qc.z, qc.w};
        unsigned int qd_[4] = {qd.x, qd.y, qd.z, qd.w};
        unsigned int r_[4];
        #pragma unroll
        for (int d = 0; d < 4; d++) {
            float2 fa = up2(qa_[d]), fb = up2(qb_[d]), fc = up2(qc_[d]), fd = up2(qd_[d]);
            float2 gg;
            gg.x = w4.x * fa.x + w4.y * fb.x + w4.z * fc.x + w4.w * fd.x;
            gg.y = w4.x * fa.y + w4.y * fb.y + w4.z * fc.y + w4.w * fd.y;
            r_[d] = pack_bf16(gg.x, gg.y);
        }
        uint4 r = {r_[0], r_[1], r_[2], r_[3]};
        int c2 = k * 8 + g;
        *(uint4*)&val_hi[c2 * 256 + ((p + c2) & 31) * 8] = r;
    }
    __syncthreads();

    // ---- stage 5: main GEMM C[64 o][32 p]; single-A reused across both p-tiles ----
    f32x4 a0 = {0.f, 0.f, 0.f, 0.f};
    f32x4 a1 = {0.f, 0.f, 0.f, 0.f};
    #pragma unroll
    for (int kk = 0; kk < NKK; kk++) {
        int abase = ((wv * NKK + kk) * 64 + lane) * 8;
        short8 ah = *(const short8*)&waM_hi[abase];
        int c2 = kk * 4 + quad;
        short8 b0 = *(const short8*)&val_hi[c2 * 256 + ((p16 + c2) & 31) * 8];
        short8 b1 = *(const short8*)&val_hi[c2 * 256 + ((16 + p16 + c2) & 31) * 8];
        a0 = __builtin_amdgcn_mfma_f32_16x16x32_bf16(ah, b0, a0, 0, 0, 0);
        a1 = __builtin_amdgcn_mfma_f32_16x16x32_bf16(ah, b1, a1, 0, 0, 0);
    }

    // ---- epilogue: direct stores ----
    size_t obase = ((size_t)n * COUT) * HW + (size_t)ho * WD + wo0;
    #pragma unroll
    for (int i = 0; i < 4; i++) {
        int o = wv * 16 + quad * 4 + i;
        float bv = bias[o];
        out[obase + (size_t)o * HW + p16] = a0[i] + bv;
        out[obase + (size_t)o * HW + 16 + p16] = a1[i] + bv;
    }
}

// ================= fallback path (R1-proven, fp32 NCHW, TPF=16) =================
__global__ void transpose_w_kernel(const float* __restrict__ w, float* __restrict__ wt) {
    int i = blockIdx.x * 256 + threadIdx.x;
    int o = i / CK;
    int ck = i - o * CK;
    wt[ck * COUT + o] = w[i];
}

__global__ __launch_bounds__(256) void offmask_kernel(
    const float* __restrict__ x,
    const float* __restrict__ w_off, const float* __restrict__ b_off,
    const float* __restrict__ w_mask, const float* __restrict__ b_mask,
    float* __restrict__ offy, float* __restrict__ offx)
{
    __shared__ float ws[CK][27];
    int t = threadIdx.x;
    for (int i = t; i < CK * 27; i += 256) {
        int j = i % 27;
        int citap = i / 27;
        int ci = citap / 9;
        int tap = citap - ci * 9;
        float v;
        if (j < 18) v = w_off[(j * CIN + ci) * 9 + tap];
        else        v = w_mask[((j - 18) * CIN + ci) * 9 + tap];
        ws[citap][j] = v;
    }
    __syncthreads();

    int pix = blockIdx.x * 256 + t;
    int n  = pix >> 14;
    int ho = (pix >> 7) & 127;
    int wo = pix & 127;

    float acc[27];
    #pragma unroll
    for (int j = 0; j < 18; j++) acc[j] = b_off[j];
    #pragma unroll
    for (int j = 0; j < 9; j++)  acc[18 + j] = b_mask[j];

    int offs[9];
    bool oks[9];
    #pragma unroll
    for (int dy = 0; dy < 3; dy++) {
        int y = ho - 1 + dy;
        #pragma unroll
        for (int dx = 0; dx < 3; dx++) {
            int xx = wo - 1 + dx;
            bool ok = (y >= 0) && (y < HD) && (xx >= 0) && (xx < WD);
            oks[dy * 3 + dx] = ok;
            offs[dy * 3 + dx] = (ok ? y : 0) * WD + (ok ? xx : 0);
        }
    }
    const float* xn = x + (size_t)n * CIN * HW;
    for (int ci = 0; ci < CIN; ci++) {
        const float* xc = xn + (size_t)ci * HW;
        float v[9];
        #pragma unroll
        for (int tap = 0; tap < 9; tap++)
            v[tap] = oks[tap] ? xc[offs[tap]] : 0.f;
        #pragma unroll
        for (int tap = 0; tap < 9; tap++) {
            const float* wrow = ws[ci * 9 + tap];
            float vv = v[tap];
            #pragma unroll
            for (int j = 0; j < 27; j++) acc[j] += wrow[j] * vv;
        }
    }
    float m[9];
    #pragma unroll
    for (int j = 0; j < 9; j++) m[j] = 1.f / (1.f + expf(-acc[18 + j]));
    #pragma unroll
    for (int k = 0; k < 9; k++) {
        int cy = 2 * k, cx = 2 * k + 1;
        float my = m[cy < 9 ? cy : cy - 9];
        float mx = m[cx < 9 ? cx : cx - 9];
        size_t o = (((size_t)n * K2 + k) * HD + ho) * WD + wo;
        offy[o] = acc[cy] * my;
        offx[o] = acc[cx] * mx;
    }
}

__global__ __launch_bounds__(256) void deform_kernel(
    const float* __restrict__ x,
    const float* __restrict__ offy, const float* __restrict__ offx,
    const float* __restrict__ wt,
    const float* __restrict__ bias,
    float* __restrict__ out)
{
    __shared__ __align__(16) float val_s[CK * TPF];
    __shared__ float4 p_w4[K2 * TPF];
    __shared__ int4   p_idx4[K2 * TPF];

    int t = threadIdx.x;
    int wo0 = blockIdx.x * TPF;
    int ho  = blockIdx.y;
    int n   = blockIdx.z;

    if (t < K2 * TPF) {
        int k = t >> 4, p = t & 15;
        int wo = wo0 + p;
        size_t oi = (((size_t)n * K2 + k) * HD + ho) * WD + wo;
        float oy = offy[oi], ox = offx[oi];
        int ki = k / 3, kj = k - ki * 3;
        float py = (float)(ho - 1 + ki) + oy;
        float px = (float)(wo - 1 + kj) + ox;
        float y0f = floorf(py), x0f = floorf(px);
        float wy = py - y0f, wx = px - x0f;
        int y0 = (int)y0f, x0 = (int)x0f;
        float wy0 = 1.f - wy, wx0 = 1.f - wx;
        int y0c = min(max(y0, 0), HD - 1);
        int y1c = min(max(y0 + 1, 0), HD - 1);
        int x0c = min(max(x0, 0), WD - 1);
        int x1c = min(max(x0 + 1, 0), WD - 1);
        bool vy0 = (y0 >= 0) && (y0 < HD);
        bool vy1 = (y0 + 1 >= 0) && (y0 + 1 < HD);
        bool vx0 = (x0 >= 0) && (x0 < WD);
        bool vx1 = (x0 + 1 >= 0) && (x0 + 1 < WD);
        float4 w4;
        w4.x = (vy0 && vx0) ? wy0 * wx0 : 0.f;
        w4.y = (vy0 && vx1) ? wy0 * wx  : 0.f;
        w4.z = (vy1 && vx0) ? wy  * wx0 : 0.f;
        w4.w = (vy1 && vx1) ? wy  * wx  : 0.f;
        int4 i4;
        i4.x = y0c * WD + x0c;
        i4.y = y0c * WD + x1c;
        i4.z = y1c * WD + x0c;
        i4.w = y1c * WD + x1c;
        p_w4[t] = w4;
        p_idx4[t] = i4;
    }
    __syncthreads();

    const float* xn = x + (size_t)n * CIN * HW;
    for (int e = t; e < CK * TPF; e += 256) {
        int row = e >> 4, p = e & 15;
        int cc = row / 9, k = row - cc * 9;
        int task = (k << 4) | p;
        float4 w4 = p_w4[task];
        int4  i4 = p_idx4[task];
        const float* xc = xn + (size_t)cc * HW;
        val_s[e] = w4.x * xc[i4.x] + w4.y * xc[i4.y]
                 + w4.z * xc[i4.z] + w4.w * xc[i4.w];
    }
    __syncthreads();

    int o = t & 63, q = t >> 6;
    float4 acc = {0.f, 0.f, 0.f, 0.f};
    const float4* v4 = (const float4*)val_s;
    const float* wp = wt + o;
    #pragma unroll 4
    for (int r = 0; r < CK; r++) {
        float w = wp[r * COUT];
        float4 vv = v4[r * 4 + q];
        acc.x += w * vv.x; acc.y += w * vv.y;
        acc.z += w * vv.z; acc.w += w * vv.w;
    }
    float b = bias[o];
    acc.x += b; acc.y += b; acc.z += b; acc.w += b;
    __syncthreads();
    float4* o4 = (float4*)val_s;
    o4[o * 4 + q] = acc;
    __syncthreads();
    size_t obase = ((size_t)n * COUT) * HW + (size_t)ho * WD + wo0;
    #pragma unroll
    for (int i = 0; i < 4; i++) {
        int l = t + 256 * i;
        int oo = l >> 4, p = l & 15;
        out[obase + (size_t)oo * HW + p] = val_s[l];
    }
}

extern "C" void kernel_launch(void* const* d_in, const int* in_sizes, int n_in,
                              void* d_out, int out_size, void* d_ws, size_t ws_size,
                              hipStream_t stream) {
    const float* x      = (const float*)d_in[0];
    const float* w_off  = (const float*)d_in[1];
    const float* b_off  = (const float*)d_in[2];
    const float* w_mask = (const float*)d_in[3];
    const float* b_mask = (const float*)d_in[4];
    const float* weight = (const float*)d_in[5];
    const float* bias   = (const float*)d_in[6];
    float* out = (float*)d_out;

    // ws layout (shorts): waM_hi | waO_hi | xp
    short* base = (short*)d_ws;
    short* waM_hi = base;
    short* waO_hi = waM_hi + WAM;
    unsigned short* xp = (unsigned short*)(waO_hi + WAO);
    size_t need = ((size_t)WAM + WAO + XTP) * sizeof(short);

    if (ws_size >= need) {
        pre_kernel<<<PRE_T + PRE_H + PRE_P, 256, 0, stream>>>(
            x, weight, w_off, w_mask, xp, waM_hi, waO_hi);
        fused_kernel<<<dim3(WD / TP, HD, NB), 256, 0, stream>>>(
            xp, waM_hi, waO_hi, b_off, b_mask, bias, out);
    } else {
        float* offy = (float*)d_ws;
        float* offx = offy + OFFSZ;
        float* wt   = offx + OFFSZ;
        transpose_w_kernel<<<144, 256, 0, stream>>>(weight, wt);
        offmask_kernel<<<256, 256, 0, stream>>>(x, w_off, b_off, w_mask, b_mask, offy, offx);
        deform_kernel<<<dim3(WD / TPF, HD, NB), 256, 0, stream>>>(x, offy, offx, wt, bias, out);
    }
}